// Round 1
// baseline (3169.976 us; speedup 1.0000x reference)
//
#include <hip/hip_runtime.h>
#include <math.h>

#define B_ 8
#define S_ 1024
#define D_ 768
#define H_ 8
#define DH_ 96
#define DFF_ 3072
#define NTOK (B_*S_)
#define EPS_ 1e-5f

// ---------------------------------------------------------------------------
// SLN: out = x * (gamma * LayerNorm(h) + beta); optionally also copy x to xcopy
// one block per row, 192 threads, float4 (768 = 192*4)
// ---------------------------------------------------------------------------
__global__ __launch_bounds__(192) void sln_kernel(
    const float* __restrict__ h, const float* __restrict__ x,
    const float* __restrict__ gamma, const float* __restrict__ beta,
    const float* __restrict__ w, const float* __restrict__ bvec,
    float* __restrict__ out, float* __restrict__ xcopy)
{
    int row = blockIdx.x;
    int t = threadIdx.x;
    const float4* h4 = (const float4*)(h + (size_t)row * D_);
    const float4* x4 = (const float4*)(x + (size_t)row * D_);
    float4 hv = h4[t];
    float s  = hv.x + hv.y + hv.z + hv.w;
    float ss = hv.x*hv.x + hv.y*hv.y + hv.z*hv.z + hv.w*hv.w;
    #pragma unroll
    for (int off = 32; off > 0; off >>= 1) {
        s  += __shfl_down(s, off);
        ss += __shfl_down(ss, off);
    }
    __shared__ float red[2][3];
    int wid = t >> 6;
    if ((t & 63) == 0) { red[0][wid] = s; red[1][wid] = ss; }
    __syncthreads();
    float sum   = red[0][0] + red[0][1] + red[0][2];
    float sumsq = red[1][0] + red[1][1] + red[1][2];
    float mu  = sum * (1.0f / D_);
    float var = sumsq * (1.0f / D_) - mu * mu;
    float rstd = rsqrtf(var + EPS_);
    float g = gamma[0], be = beta[0];
    float4 wv = ((const float4*)w)[t];
    float4 bv = ((const float4*)bvec)[t];
    float4 xv = x4[t];
    float4 o;
    o.x = xv.x * (g * ((hv.x - mu) * rstd * wv.x + bv.x) + be);
    o.y = xv.y * (g * ((hv.y - mu) * rstd * wv.y + bv.y) + be);
    o.z = xv.z * (g * ((hv.z - mu) * rstd * wv.z + bv.z) + be);
    o.w = xv.w * (g * ((hv.w - mu) * rstd * wv.w + bv.w) + be);
    ((float4*)(out + (size_t)row * D_))[t] = o;
    if (xcopy) ((float4*)(xcopy + (size_t)row * D_))[t] = xv;
}

// ---------------------------------------------------------------------------
// fp32 GEMM: C[M,N] = A[M,K] @ W[K,N] + bias (+relu) (+resid)
// 64x64 tile, BK=16, 256 threads, 4x4 micro-tile per thread
// ---------------------------------------------------------------------------
#define BM 64
#define BN 64
#define BK 16

__global__ __launch_bounds__(256) void gemm_kernel(
    const float* __restrict__ A, const float* __restrict__ Wt,
    const float* __restrict__ bias, const float* __restrict__ resid,
    float* __restrict__ C, int M, int K, int Nn, int do_relu)
{
    __shared__ float As[BK][BM + 4];
    __shared__ float Bs[BK][BN + 4];
    int t  = threadIdx.x;
    int tx = t & 15, ty = t >> 4;
    int bm = blockIdx.x * BM;
    int bn = blockIdx.y * BN;

    int arow = t >> 2;          // 0..63
    int akq  = (t & 3) * 4;     // 0,4,8,12
    int brow = t >> 4;          // 0..15
    int bcol = (t & 15) * 4;

    const float* Aptr = A  + (size_t)(bm + arow) * K + akq;
    const float* Bptr = Wt + (size_t)brow * Nn + bn + bcol;

    float acc[4][4] = {};

    for (int k0 = 0; k0 < K; k0 += BK) {
        float4 av = *(const float4*)(Aptr + k0);
        float4 bv = *(const float4*)(Bptr + (size_t)k0 * Nn);
        __syncthreads();
        As[akq + 0][arow] = av.x;
        As[akq + 1][arow] = av.y;
        As[akq + 2][arow] = av.z;
        As[akq + 3][arow] = av.w;
        *(float4*)&Bs[brow][bcol] = bv;
        __syncthreads();
        #pragma unroll
        for (int kk = 0; kk < BK; kk++) {
            float a0 = As[kk][ty * 4 + 0];
            float a1 = As[kk][ty * 4 + 1];
            float a2 = As[kk][ty * 4 + 2];
            float a3 = As[kk][ty * 4 + 3];
            float4 b4 = *(const float4*)&Bs[kk][tx * 4];
            acc[0][0] += a0 * b4.x; acc[0][1] += a0 * b4.y; acc[0][2] += a0 * b4.z; acc[0][3] += a0 * b4.w;
            acc[1][0] += a1 * b4.x; acc[1][1] += a1 * b4.y; acc[1][2] += a1 * b4.z; acc[1][3] += a1 * b4.w;
            acc[2][0] += a2 * b4.x; acc[2][1] += a2 * b4.y; acc[2][2] += a2 * b4.z; acc[2][3] += a2 * b4.w;
            acc[3][0] += a3 * b4.x; acc[3][1] += a3 * b4.y; acc[3][2] += a3 * b4.z; acc[3][3] += a3 * b4.w;
        }
    }

    float4 bias4 = *(const float4*)&bias[bn + tx * 4];
    #pragma unroll
    for (int i = 0; i < 4; i++) {
        int row = bm + ty * 4 + i;
        float4 o;
        o.x = acc[i][0] + bias4.x;
        o.y = acc[i][1] + bias4.y;
        o.z = acc[i][2] + bias4.z;
        o.w = acc[i][3] + bias4.w;
        if (do_relu) {
            o.x = fmaxf(o.x, 0.f); o.y = fmaxf(o.y, 0.f);
            o.z = fmaxf(o.z, 0.f); o.w = fmaxf(o.w, 0.f);
        }
        if (resid) {
            float4 rv = *(const float4*)&resid[(size_t)row * Nn + bn + tx * 4];
            o.x += rv.x; o.y += rv.y; o.z += rv.z; o.w += rv.w;
        }
        *(float4*)&C[(size_t)row * Nn + bn + tx * 4] = o;
    }
}

// ---------------------------------------------------------------------------
// L2-distance attention, flash-style online softmax.
// grid = B*H*(S/TQ); block = 256. 16 query rows/block, 32-key tiles.
// q,k,v layout: [B,S,H*DH] (row = b*S+s, col = h*DH+dh). out same layout.
// ---------------------------------------------------------------------------
#define TQ 16
#define TK 32

__global__ __launch_bounds__(256) void attn_kernel(
    const float* __restrict__ q, const float* __restrict__ k,
    const float* __restrict__ v, float* __restrict__ out)
{
    int qt = blockIdx.x & (S_ / TQ - 1);   // 0..63
    int bh = blockIdx.x >> 6;              // 0..63
    int b  = bh >> 3;
    int hh = bh & 7;

    __shared__ float Qs[TQ][DH_ + 1];
    __shared__ float Ks[TK][DH_ + 1];
    __shared__ float Vs[TK][DH_ + 1];
    __shared__ float Ps[TQ][TK + 1];
    __shared__ float q2s[TQ], k2s[TK], mrow[TQ], lrow[TQ], arow_s[TQ];

    int t = threadIdx.x;

    const float* qbase = q + ((size_t)(b * S_ + qt * TQ)) * D_ + hh * DH_;
    for (int f = t; f < TQ * DH_; f += 256) {
        int r = f / DH_, c = f % DH_;
        Qs[r][c] = qbase[(size_t)r * D_ + c];
    }
    __syncthreads();
    if (t < TQ) {
        float s2 = 0.f;
        for (int c = 0; c < DH_; c++) { float qv = Qs[t][c]; s2 += qv * qv; }
        q2s[t] = s2; mrow[t] = -INFINITY; lrow[t] = 0.f;
    }

    float acc[6] = {0.f, 0.f, 0.f, 0.f, 0.f, 0.f};
    int pr = t >> 4;           // 0..15   PV row
    int pc = (t & 15) * 6;     // PV col base (16*6 = 96)
    int sr = t >> 5;           // 0..7    score row base
    int sj = t & 31;           // score col
    const float rs = 0.10206207261596575f;   // 1/sqrt(96)

    for (int kt = 0; kt < S_ / TK; kt++) {
        __syncthreads();
        const float* kbase = k + ((size_t)(b * S_ + kt * TK)) * D_ + hh * DH_;
        const float* vbase = v + ((size_t)(b * S_ + kt * TK)) * D_ + hh * DH_;
        for (int f = t; f < TK * DH_; f += 256) {
            int r = f / DH_, c = f % DH_;
            Ks[r][c] = kbase[(size_t)r * D_ + c];
            Vs[r][c] = vbase[(size_t)r * D_ + c];
        }
        __syncthreads();
        if (t < TK) {
            float s2 = 0.f;
            for (int c = 0; c < DH_; c++) { float kv = Ks[t][c]; s2 += kv * kv; }
            k2s[t] = s2;
        }
        __syncthreads();
        // scores for rows sr and sr+8, column sj
        {
            float d0 = 0.f, d1 = 0.f;
            for (int c = 0; c < DH_; c++) {
                float kv = Ks[sj][c];
                d0 += Qs[sr][c] * kv;
                d1 += Qs[sr + 8][c] * kv;
            }
            float k2v = k2s[sj];
            float e0 = fmaxf(q2s[sr]     + k2v - 2.f * d0, 0.f);
            float e1 = fmaxf(q2s[sr + 8] + k2v - 2.f * d1, 0.f);
            Ps[sr][sj]     = -sqrtf(e0) * rs;
            Ps[sr + 8][sj] = -sqrtf(e1) * rs;
        }
        __syncthreads();
        if (t < TQ) {
            float m = mrow[t];
            float tm = m;
            for (int j = 0; j < TK; j++) tm = fmaxf(tm, Ps[t][j]);
            float al = __expf(m - tm);     // 0 on first tile (m = -inf)
            float ssum = 0.f;
            for (int j = 0; j < TK; j++) {
                float p = __expf(Ps[t][j] - tm);
                Ps[t][j] = p;
                ssum += p;
            }
            lrow[t] = lrow[t] * al + ssum;
            mrow[t] = tm;
            arow_s[t] = al;
        }
        __syncthreads();
        float al = arow_s[pr];
        #pragma unroll
        for (int cc = 0; cc < 6; cc++) acc[cc] *= al;
        for (int j = 0; j < TK; j++) {
            float p = Ps[pr][j];
            #pragma unroll
            for (int cc = 0; cc < 6; cc++) acc[cc] += p * Vs[j][pc + cc];
        }
    }
    float inv_l = 1.f / lrow[pr];
    float* obase = out + ((size_t)(b * S_ + qt * TQ + pr)) * D_ + hh * DH_ + pc;
    #pragma unroll
    for (int cc = 0; cc < 6; cc++) obase[cc] = acc[cc] * inv_l;
}

// ---------------------------------------------------------------------------
extern "C" void kernel_launch(void* const* d_in, const int* in_sizes, int n_in,
                              void* d_out, int out_size, void* d_ws, size_t ws_size,
                              hipStream_t stream)
{
    const float* h    = (const float*)d_in[0];
    const float* x    = (const float*)d_in[1];
    const float* g1   = (const float*)d_in[2];
    const float* be1  = (const float*)d_in[3];
    const float* ln1w = (const float*)d_in[4];
    const float* ln1b = (const float*)d_in[5];
    const float* g2   = (const float*)d_in[6];
    const float* be2  = (const float*)d_in[7];
    const float* ln2w = (const float*)d_in[8];
    const float* ln2b = (const float*)d_in[9];
    const float* Wq   = (const float*)d_in[10];
    const float* bq   = (const float*)d_in[11];
    const float* Wk   = (const float*)d_in[12];
    const float* bk   = (const float*)d_in[13];
    const float* Wv   = (const float*)d_in[14];
    const float* bv   = (const float*)d_in[15];
    const float* Wo   = (const float*)d_in[16];
    const float* bo   = (const float*)d_in[17];
    const float* W1   = (const float*)d_in[18];
    const float* b1   = (const float*)d_in[19];
    const float* W2   = (const float*)d_in[20];
    const float* b2   = (const float*)d_in[21];

    float* out = (float*)d_out;
    float* ws  = (float*)d_ws;

    const size_t ND = (size_t)NTOK * D_;
    float* h1     = ws;            // also reused as attn_out
    float* qb     = ws + ND;       // also reused as h2
    float* kb     = ws + 2 * ND;
    float* vb     = ws + 3 * ND;
    float* htmp   = ws + 4 * ND;
    float* hidden = ws + 5 * ND;

    // MLP hidden chunking based on available workspace
    size_t avail = ws_size / sizeof(float);
    int chunk = 64;
    if (avail > 5 * ND + 64 * (size_t)DFF_) {
        size_t c = (avail - 5 * ND) / DFF_;
        c = (c / 64) * 64;
        if (c > (size_t)NTOK) c = NTOK;
        chunk = (int)c;
    }

    // 1. SLN1 (+ copy x into d_out[0:ND])
    sln_kernel<<<NTOK, 192, 0, stream>>>(h, x, g1, be1, ln1w, ln1b, h1, out);

    // 2. QKV projections
    dim3 gproj(NTOK / BM, D_ / BN);
    gemm_kernel<<<gproj, 256, 0, stream>>>(h1, Wq, bq, nullptr, qb, NTOK, D_, D_, 0);
    gemm_kernel<<<gproj, 256, 0, stream>>>(h1, Wk, bk, nullptr, kb, NTOK, D_, D_, 0);
    gemm_kernel<<<gproj, 256, 0, stream>>>(h1, Wv, bv, nullptr, vb, NTOK, D_, D_, 0);

    // 3. attention -> h1 (attn_out)
    attn_kernel<<<B_ * H_ * (S_ / TQ), 256, 0, stream>>>(qb, kb, vb, h1);

    // 4. output projection + residual h -> htmp
    gemm_kernel<<<gproj, 256, 0, stream>>>(h1, Wo, bo, h, htmp, NTOK, D_, D_, 0);

    // 5. SLN2 -> h2 (reuse qb)
    sln_kernel<<<NTOK, 192, 0, stream>>>(htmp, x, g2, be2, ln2w, ln2b, qb, nullptr);

    // 6. MLP (chunked over rows): hf = relu(h2@W1+b1)@W2 + b2 + htmp
    for (int r0 = 0; r0 < NTOK; r0 += chunk) {
        int rows = NTOK - r0;
        if (rows > chunk) rows = chunk;
        dim3 g1_(rows / BM, DFF_ / BN);
        gemm_kernel<<<g1_, 256, 0, stream>>>(qb + (size_t)r0 * D_, W1, b1, nullptr,
                                             hidden, rows, D_, DFF_, 1);
        dim3 g2_(rows / BM, D_ / BN);
        gemm_kernel<<<g2_, 256, 0, stream>>>(hidden, W2, b2, htmp + (size_t)r0 * D_,
                                             out + ND + (size_t)r0 * D_, rows, DFF_, D_, 0);
    }
}

// Round 2
// 1898.694 us; speedup vs baseline: 1.6696x; 1.6696x over previous
//
#include <hip/hip_runtime.h>
#include <math.h>

#define B_ 8
#define S_ 1024
#define D_ 768
#define H_ 8
#define DH_ 96
#define DFF_ 3072
#define NTOK (B_*S_)
#define QKVW 2304            // fused q|k|v width
#define EPS_ 1e-5f

typedef __attribute__((ext_vector_type(4))) float f4;
typedef __attribute__((ext_vector_type(4))) int i4;
typedef __attribute__((ext_vector_type(8))) __bf16 bf16x8;
typedef __attribute__((ext_vector_type(4))) unsigned short us4;

static __device__ __forceinline__ unsigned short f2bf(float f) {
    unsigned int u = __builtin_bit_cast(unsigned int, f);
    u += 0x7fffu + ((u >> 16) & 1u);
    return (unsigned short)(u >> 16);
}
static __device__ __forceinline__ float bf2f(unsigned short u) {
    unsigned int x = ((unsigned int)u) << 16;
    return __builtin_bit_cast(float, x);
}

#define GLOBAL_LOAD_LDS16(g, l) \
    __builtin_amdgcn_global_load_lds((const __attribute__((address_space(1))) unsigned int*)(g), \
                                     (__attribute__((address_space(3))) unsigned int*)(l), 16, 0, 0)

// ---------------------------------------------------------------------------
// SLN: out_bf16 = bf16( x * (gamma * LayerNorm(h) + beta) ); optional x copy (fp32)
// one block per row, 192 threads, float4 (768 = 192*4)
// ---------------------------------------------------------------------------
__global__ __launch_bounds__(192) void sln_kernel(
    const float* __restrict__ h, const float* __restrict__ x,
    const float* __restrict__ gamma, const float* __restrict__ beta,
    const float* __restrict__ w, const float* __restrict__ bvec,
    unsigned short* __restrict__ out_bf, float* __restrict__ xcopy)
{
    int row = blockIdx.x;
    int t = threadIdx.x;
    const float4* h4 = (const float4*)(h + (size_t)row * D_);
    const float4* x4 = (const float4*)(x + (size_t)row * D_);
    float4 hv = h4[t];
    float s  = hv.x + hv.y + hv.z + hv.w;
    float ss = hv.x*hv.x + hv.y*hv.y + hv.z*hv.z + hv.w*hv.w;
    #pragma unroll
    for (int off = 32; off > 0; off >>= 1) {
        s  += __shfl_down(s, off);
        ss += __shfl_down(ss, off);
    }
    __shared__ float red[2][3];
    int wid = t >> 6;
    if ((t & 63) == 0) { red[0][wid] = s; red[1][wid] = ss; }
    __syncthreads();
    float sum   = red[0][0] + red[0][1] + red[0][2];
    float sumsq = red[1][0] + red[1][1] + red[1][2];
    float mu  = sum * (1.0f / D_);
    float var = sumsq * (1.0f / D_) - mu * mu;
    float rstd = rsqrtf(var + EPS_);
    float g = gamma[0], be = beta[0];
    float4 wv = ((const float4*)w)[t];
    float4 bv = ((const float4*)bvec)[t];
    float4 xv = x4[t];
    us4 o;
    o.x = f2bf(xv.x * (g * ((hv.x - mu) * rstd * wv.x + bv.x) + be));
    o.y = f2bf(xv.y * (g * ((hv.y - mu) * rstd * wv.y + bv.y) + be));
    o.z = f2bf(xv.z * (g * ((hv.z - mu) * rstd * wv.z + bv.z) + be));
    o.w = f2bf(xv.w * (g * ((hv.w - mu) * rstd * wv.w + bv.w) + be));
    *(us4*)(out_bf + (size_t)row * D_ + t * 4) = o;
    if (xcopy) ((float4*)(xcopy + (size_t)row * D_))[t] = xv;
}

// ---------------------------------------------------------------------------
// Tiled transpose + fp32->bf16: in [K][N] fp32 -> out [N][K] bf16
// ---------------------------------------------------------------------------
__global__ __launch_bounds__(256) void transpose_bf16_kernel(
    const float* __restrict__ in, unsigned short* __restrict__ out, int K, int N)
{
    __shared__ float tile[32][33];
    int n0 = blockIdx.x * 32, k0 = blockIdx.y * 32;
    int tx = threadIdx.x, ty = threadIdx.y;   // 32 x 8
    #pragma unroll
    for (int r = 0; r < 4; r++)
        tile[ty + r * 8][tx] = in[(size_t)(k0 + ty + r * 8) * N + n0 + tx];
    __syncthreads();
    #pragma unroll
    for (int r = 0; r < 4; r++)
        out[(size_t)(n0 + ty + r * 8) * K + k0 + tx] = f2bf(tile[tx][ty + r * 8]);
}

__global__ void concat_bias_kernel(const float* __restrict__ bq, const float* __restrict__ bk,
                                   const float* __restrict__ bv, float* __restrict__ outb)
{
    int i = blockIdx.x * 256 + threadIdx.x;
    if (i >= QKVW) return;
    float v = (i < 768) ? bq[i] : (i < 1536) ? bk[i - 768] : bv[i - 1536];
    outb[i] = v;
}

// ---------------------------------------------------------------------------
// bf16 MFMA GEMM (m97-style): C[M,N] = A[M,K] @ Bt[N,K]^T + bias (+relu)(+resid)
// 128x128 tile, BK=32, 256 threads = 4 waves in 2x2, each wave 4x4 of 16x16x32.
// A, Bt row-major bf16. out fp32 or bf16 (template).
// ---------------------------------------------------------------------------
template<int OUT_BF16, int RELU>
__global__ __launch_bounds__(256) void gemm_mfma_kernel(
    const unsigned short* __restrict__ A, const unsigned short* __restrict__ Bt,
    const float* __restrict__ bias, const float* __restrict__ resid,
    void* __restrict__ Cout, int M, int N, int K)
{
    __shared__ unsigned short Asm[128 * 32];
    __shared__ unsigned short Bsm[128 * 32];

    int t = threadIdx.x;
    int lane = t & 63, wv = t >> 6;
    int wm = wv & 1, wn = wv >> 1;
    int l16 = lane & 15, quad = lane >> 4;

    int bm = blockIdx.x * 128;
    int bn = blockIdx.y * 128;

    const unsigned short* Abase = A  + (size_t)bm * K;
    const unsigned short* Bbase = Bt + (size_t)bn * K;

    // staging chunk ids
    int fl0 = t, fl1 = 256 + t;
    int r0s = fl0 >> 2, kc0 = (fl0 & 3) << 3;
    int r1s = fl1 >> 2, kc1 = (fl1 & 3) << 3;

    f4 acc[4][4] = {};

    for (int k0 = 0; k0 < K; k0 += 32) {
        __syncthreads();
        GLOBAL_LOAD_LDS16(Abase + (size_t)r0s * K + k0 + kc0, &Asm[fl0 * 8]);
        GLOBAL_LOAD_LDS16(Abase + (size_t)r1s * K + k0 + kc1, &Asm[fl1 * 8]);
        GLOBAL_LOAD_LDS16(Bbase + (size_t)r0s * K + k0 + kc0, &Bsm[fl0 * 8]);
        GLOBAL_LOAD_LDS16(Bbase + (size_t)r1s * K + k0 + kc1, &Bsm[fl1 * 8]);
        __syncthreads();

        bf16x8 af[4], bf[4];
        #pragma unroll
        for (int i = 0; i < 4; i++) {
            int m = wm * 64 + i * 16 + l16;
            af[i] = __builtin_bit_cast(bf16x8, *(const i4*)&Asm[m * 32 + quad * 8]);
        }
        #pragma unroll
        for (int j = 0; j < 4; j++) {
            int n = wn * 64 + j * 16 + l16;
            bf[j] = __builtin_bit_cast(bf16x8, *(const i4*)&Bsm[n * 32 + quad * 8]);
        }
        #pragma unroll
        for (int i = 0; i < 4; i++)
            #pragma unroll
            for (int j = 0; j < 4; j++)
                acc[i][j] = __builtin_amdgcn_mfma_f32_16x16x32_bf16(af[i], bf[j], acc[i][j], 0, 0, 0);
    }

    // epilogue
    #pragma unroll
    for (int j = 0; j < 4; j++) {
        int colg = bn + wn * 64 + j * 16 + l16;
        float bv = bias ? bias[colg] : 0.f;
        #pragma unroll
        for (int i = 0; i < 4; i++) {
            #pragma unroll
            for (int r = 0; r < 4; r++) {
                int rowg = bm + wm * 64 + i * 16 + quad * 4 + r;
                float v = acc[i][j][r] + bv;
                if (RELU) v = fmaxf(v, 0.f);
                if (resid) v += resid[(size_t)rowg * N + colg];
                if (OUT_BF16)
                    ((unsigned short*)Cout)[(size_t)rowg * N + colg] = f2bf(v);
                else
                    ((float*)Cout)[(size_t)rowg * N + colg] = v;
            }
        }
    }
}

// ---------------------------------------------------------------------------
// q2/k2 norms from fused qkv bf16 buffer [NTOK][2304] -> q2g,k2g [B*H*S] fp32
// one block per token row; thread = (head = t>>5, lane32 = t&31), 3 elems each
// ---------------------------------------------------------------------------
__global__ __launch_bounds__(256) void norms_kernel(
    const unsigned short* __restrict__ qkv, float* __restrict__ q2g, float* __restrict__ k2g)
{
    int row = blockIdx.x;
    int t = threadIdx.x;
    int hh = t >> 5, l32 = t & 31;
    const unsigned short* base = qkv + (size_t)row * QKVW + hh * DH_ + l32 * 3;
    float qs = 0.f, ks = 0.f;
    #pragma unroll
    for (int e = 0; e < 3; e++) {
        float qv = bf2f(base[e]);
        float kv = bf2f(base[768 + e]);
        qs += qv * qv; ks += kv * kv;
    }
    #pragma unroll
    for (int off = 16; off > 0; off >>= 1) {
        qs += __shfl_xor(qs, off, 32);
        ks += __shfl_xor(ks, off, 32);
    }
    if (l32 == 0) {
        int b = row >> 10, s = row & 1023;
        int idx = (b * H_ + hh) * S_ + s;
        q2g[idx] = qs; k2g[idx] = ks;
    }
}

// ---------------------------------------------------------------------------
// L2-distance attention, flash-style. bf16 in (fused qkv layout), bf16 out.
// grid = B*H*(S/TQ); block 256. TQ=16 query rows, TK=32 key tiles.
// ---------------------------------------------------------------------------
#define TQ 16
#define TK 32

__global__ __launch_bounds__(256) void attn_kernel(
    const unsigned short* __restrict__ qkv,
    const float* __restrict__ q2g, const float* __restrict__ k2g,
    unsigned short* __restrict__ outb)
{
    int qt = blockIdx.x & (S_ / TQ - 1);   // 0..63
    int bh = blockIdx.x >> 6;              // 0..63
    int b  = bh >> 3;
    int hh = bh & 7;

    __shared__ float Qs[TQ][DH_ + 1];
    __shared__ float Ks[TK][DH_ + 1];
    __shared__ float Vs[TK][DH_ + 1];
    __shared__ float Ps[TQ][TK + 1];
    __shared__ float q2s[TQ], mrow[TQ], lrow[TQ], arow_s[TQ];

    int t = threadIdx.x;

    const unsigned short* qbase = qkv + ((size_t)(b * S_ + qt * TQ)) * QKVW + hh * DH_;
    for (int p = t; p < TQ * 48; p += 256) {
        int r = p / 48, c = (p % 48) * 2;
        unsigned int uv = *(const unsigned int*)(qbase + (size_t)r * QKVW + c);
        Qs[r][c]     = bf2f((unsigned short)(uv & 0xffff));
        Qs[r][c + 1] = bf2f((unsigned short)(uv >> 16));
    }
    if (t < TQ) {
        q2s[t] = q2g[bh * S_ + qt * TQ + t];
        mrow[t] = -INFINITY; lrow[t] = 0.f;
    }

    float acc[6] = {0.f, 0.f, 0.f, 0.f, 0.f, 0.f};
    int pr = t >> 4;           // PV row
    int pc = (t & 15) * 6;     // PV col base
    int sr = t >> 5;           // score row base (0..7)
    int sj = t & 31;           // score col
    int sxr = t >> 4;          // softmax row
    int sxc = (t & 15) * 2;    // softmax col base
    const float rs = 0.10206207261596575f;   // 1/sqrt(96)

    const unsigned short* kvbase0 = qkv + ((size_t)(b * S_)) * QKVW + hh * DH_;

    for (int kt = 0; kt < S_ / TK; kt++) {
        __syncthreads();
        const unsigned short* kbase = kvbase0 + (size_t)(kt * TK) * QKVW + 768;
        for (int p = t; p < TK * 48; p += 256) {
            int r = p / 48, c = (p % 48) * 2;
            const unsigned short* rp = kbase + (size_t)r * QKVW + c;
            unsigned int ku = *(const unsigned int*)rp;
            unsigned int vu = *(const unsigned int*)(rp + 768);
            Ks[r][c]     = bf2f((unsigned short)(ku & 0xffff));
            Ks[r][c + 1] = bf2f((unsigned short)(ku >> 16));
            Vs[r][c]     = bf2f((unsigned short)(vu & 0xffff));
            Vs[r][c + 1] = bf2f((unsigned short)(vu >> 16));
        }
        __syncthreads();
        // scores for rows sr, sr+8 at column sj
        {
            float d0 = 0.f, d1 = 0.f;
            #pragma unroll 8
            for (int c = 0; c < DH_; c++) {
                float kv = Ks[sj][c];
                d0 += Qs[sr][c] * kv;
                d1 += Qs[sr + 8][c] * kv;
            }
            float k2v = k2g[bh * S_ + kt * TK + sj];
            float e0 = fmaxf(q2s[sr]     + k2v - 2.f * d0, 0.f);
            float e1 = fmaxf(q2s[sr + 8] + k2v - 2.f * d1, 0.f);
            Ps[sr][sj]     = -sqrtf(e0) * rs;
            Ps[sr + 8][sj] = -sqrtf(e1) * rs;
        }
        __syncthreads();
        // parallel online softmax: 16 lanes per row, 2 cols each
        {
            float p0 = Ps[sxr][sxc], p1 = Ps[sxr][sxc + 1];
            float tm = fmaxf(p0, p1);
            #pragma unroll
            for (int off = 1; off < 16; off <<= 1)
                tm = fmaxf(tm, __shfl_xor(tm, off, 16));
            float mprev = mrow[sxr];
            float tmax = fmaxf(mprev, tm);
            float e0 = __expf(p0 - tmax), e1 = __expf(p1 - tmax);
            Ps[sxr][sxc] = e0; Ps[sxr][sxc + 1] = e1;
            float ssum = e0 + e1;
            #pragma unroll
            for (int off = 1; off < 16; off <<= 1)
                ssum += __shfl_xor(ssum, off, 16);
            if ((t & 15) == 0) {
                float al = __expf(mprev - tmax);
                lrow[sxr] = lrow[sxr] * al + ssum;
                mrow[sxr] = tmax;
                arow_s[sxr] = al;
            }
        }
        __syncthreads();
        float al = arow_s[pr];
        #pragma unroll
        for (int cc = 0; cc < 6; cc++) acc[cc] *= al;
        for (int j = 0; j < TK; j++) {
            float p = Ps[pr][j];
            #pragma unroll
            for (int cc = 0; cc < 6; cc++) acc[cc] += p * Vs[j][pc + cc];
        }
    }
    float inv_l = 1.f / lrow[pr];
    unsigned short* obase = outb + ((size_t)(b * S_ + qt * TQ + pr)) * D_ + hh * DH_ + pc;
    #pragma unroll
    for (int cc = 0; cc < 6; cc++) obase[cc] = f2bf(acc[cc] * inv_l);
}

// ---------------------------------------------------------------------------
extern "C" void kernel_launch(void* const* d_in, const int* in_sizes, int n_in,
                              void* d_out, int out_size, void* d_ws, size_t ws_size,
                              hipStream_t stream)
{
    const float* h    = (const float*)d_in[0];
    const float* x    = (const float*)d_in[1];
    const float* g1   = (const float*)d_in[2];
    const float* be1  = (const float*)d_in[3];
    const float* ln1w = (const float*)d_in[4];
    const float* ln1b = (const float*)d_in[5];
    const float* g2   = (const float*)d_in[6];
    const float* be2  = (const float*)d_in[7];
    const float* ln2w = (const float*)d_in[8];
    const float* ln2b = (const float*)d_in[9];
    const float* Wq   = (const float*)d_in[10];
    const float* bq   = (const float*)d_in[11];
    const float* Wk   = (const float*)d_in[12];
    const float* bk   = (const float*)d_in[13];
    const float* Wv   = (const float*)d_in[14];
    const float* bv   = (const float*)d_in[15];
    const float* Wo   = (const float*)d_in[16];
    const float* bo   = (const float*)d_in[17];
    const float* W1   = (const float*)d_in[18];
    const float* b1   = (const float*)d_in[19];
    const float* W2   = (const float*)d_in[20];
    const float* b2   = (const float*)d_in[21];

    float* out = (float*)d_out;
    char* wsb = (char*)d_ws;
    const size_t ND = (size_t)NTOK * D_;

    // workspace layout (bytes)
    unsigned short* Wqkvt = (unsigned short*)(wsb);                       // [2304][768]
    unsigned short* Wot   = (unsigned short*)(wsb + 3538944);             // [768][768]
    unsigned short* W1t   = (unsigned short*)(wsb + 3538944 + 1179648);   // [3072][768]
    unsigned short* W2t   = (unsigned short*)(wsb + 3538944 + 1179648 + 4718592); // [768][3072]
    size_t off = 3538944 + 1179648 + 4718592 + 4718592;
    float* bqkv = (float*)(wsb + off);            off += 16384;
    unsigned short* h1b   = (unsigned short*)(wsb + off); off += ND * 2;   // alias: attnb
    unsigned short* qkvb  = (unsigned short*)(wsb + off); off += (size_t)NTOK * QKVW * 2;
    float* q2g  = (float*)(wsb + off);            off += (size_t)B_ * H_ * S_ * 4;
    float* k2g  = (float*)(wsb + off);            off += (size_t)B_ * H_ * S_ * 4;
    float* htmp = (float*)(wsb + off);            off += ND * 4;
    unsigned short* attnb   = h1b;                         // h1b dead after QKV GEMM
    unsigned short* h2b     = qkvb;                        // qkvb dead after attention
    unsigned short* hiddenb = qkvb + ND;                   // chunk [4096][3072] bf16

    // --- weight prep (transpose + bf16) ---
    dim3 tb(32, 8);
    transpose_bf16_kernel<<<dim3(768/32, 768/32), tb, 0, stream>>>(Wq, Wqkvt,              768, 768);
    transpose_bf16_kernel<<<dim3(768/32, 768/32), tb, 0, stream>>>(Wk, Wqkvt + 768*768,    768, 768);
    transpose_bf16_kernel<<<dim3(768/32, 768/32), tb, 0, stream>>>(Wv, Wqkvt + 2*768*768,  768, 768);
    transpose_bf16_kernel<<<dim3(768/32, 768/32), tb, 0, stream>>>(Wo, Wot, 768, 768);
    transpose_bf16_kernel<<<dim3(3072/32, 768/32), tb, 0, stream>>>(W1, W1t, 768, 3072);
    transpose_bf16_kernel<<<dim3(768/32, 3072/32), tb, 0, stream>>>(W2, W2t, 3072, 768);
    concat_bias_kernel<<<9, 256, 0, stream>>>(bq, bk, bv, bqkv);

    // 1. SLN1 -> h1b (bf16), copy x -> out[0:ND]
    sln_kernel<<<NTOK, 192, 0, stream>>>(h, x, g1, be1, ln1w, ln1b, h1b, out);

    // 2. fused QKV GEMM: [8192,768] @ [768,2304] -> qkvb bf16
    gemm_mfma_kernel<1, 0><<<dim3(NTOK/128, QKVW/128), 256, 0, stream>>>(
        h1b, Wqkvt, bqkv, nullptr, qkvb, NTOK, QKVW, D_);

    // 3. norms
    norms_kernel<<<NTOK, 256, 0, stream>>>(qkvb, q2g, k2g);

    // 4. attention -> attnb bf16
    attn_kernel<<<B_ * H_ * (S_ / TQ), 256, 0, stream>>>(qkvb, q2g, k2g, attnb);

    // 5. Wo projection + residual h -> htmp fp32
    gemm_mfma_kernel<0, 0><<<dim3(NTOK/128, D_/128), 256, 0, stream>>>(
        attnb, Wot, bo, h, htmp, NTOK, D_, D_);

    // 6. SLN2 -> h2b bf16
    sln_kernel<<<NTOK, 192, 0, stream>>>(htmp, x, g2, be2, ln2w, ln2b, h2b, nullptr);

    // 7. MLP in 2 row-chunks of 4096
    for (int r0 = 0; r0 < NTOK; r0 += 4096) {
        gemm_mfma_kernel<1, 1><<<dim3(4096/128, DFF_/128), 256, 0, stream>>>(
            h2b + (size_t)r0 * D_, W1t, b1, nullptr, hiddenb, 4096, DFF_, D_);
        gemm_mfma_kernel<0, 0><<<dim3(4096/128, D_/128), 256, 0, stream>>>(
            hiddenb, W2t, b2, htmp + (size_t)r0 * D_, out + ND + (size_t)r0 * D_, 4096, D_, DFF_);
    }
    (void)in_sizes; (void)n_in; (void)out_size; (void)ws_size;
}

// Round 3
// 633.056 us; speedup vs baseline: 5.0074x; 2.9993x over previous
//
#include <hip/hip_runtime.h>
#include <math.h>

#define B_ 8
#define S_ 1024
#define D_ 768
#define H_ 8
#define DH_ 96
#define DFF_ 3072
#define NTOK (B_*S_)
#define QKVW 2304            // fused q|k|v width
#define EPS_ 1e-5f

typedef __attribute__((ext_vector_type(4))) float f4;
typedef __attribute__((ext_vector_type(4))) int i4;
typedef __attribute__((ext_vector_type(8))) __bf16 bf16x8;
typedef __attribute__((ext_vector_type(4))) unsigned short us4;
typedef __attribute__((ext_vector_type(8))) unsigned short us8;

static __device__ __forceinline__ unsigned short f2bf(float f) {
    unsigned int u = __builtin_bit_cast(unsigned int, f);
    u += 0x7fffu + ((u >> 16) & 1u);
    return (unsigned short)(u >> 16);
}
static __device__ __forceinline__ float bf2f(unsigned short u) {
    unsigned int x = ((unsigned int)u) << 16;
    return __builtin_bit_cast(float, x);
}

#define GLOBAL_LOAD_LDS16(g, l) \
    __builtin_amdgcn_global_load_lds((const __attribute__((address_space(1))) unsigned int*)(g), \
                                     (__attribute__((address_space(3))) unsigned int*)(l), 16, 0, 0)

// ---------------------------------------------------------------------------
// SLN: out_bf16 = bf16( x * (gamma * LayerNorm(h) + beta) ); optional x copy (fp32)
// ---------------------------------------------------------------------------
__global__ __launch_bounds__(192) void sln_kernel(
    const float* __restrict__ h, const float* __restrict__ x,
    const float* __restrict__ gamma, const float* __restrict__ beta,
    const float* __restrict__ w, const float* __restrict__ bvec,
    unsigned short* __restrict__ out_bf, float* __restrict__ xcopy)
{
    int row = blockIdx.x;
    int t = threadIdx.x;
    const float4* h4 = (const float4*)(h + (size_t)row * D_);
    const float4* x4 = (const float4*)(x + (size_t)row * D_);
    float4 hv = h4[t];
    float s  = hv.x + hv.y + hv.z + hv.w;
    float ss = hv.x*hv.x + hv.y*hv.y + hv.z*hv.z + hv.w*hv.w;
    #pragma unroll
    for (int off = 32; off > 0; off >>= 1) {
        s  += __shfl_down(s, off);
        ss += __shfl_down(ss, off);
    }
    __shared__ float red[2][3];
    int wid = t >> 6;
    if ((t & 63) == 0) { red[0][wid] = s; red[1][wid] = ss; }
    __syncthreads();
    float sum   = red[0][0] + red[0][1] + red[0][2];
    float sumsq = red[1][0] + red[1][1] + red[1][2];
    float mu  = sum * (1.0f / D_);
    float var = sumsq * (1.0f / D_) - mu * mu;
    float rstd = rsqrtf(var + EPS_);
    float g = gamma[0], be = beta[0];
    float4 wv = ((const float4*)w)[t];
    float4 bv = ((const float4*)bvec)[t];
    float4 xv = x4[t];
    us4 o;
    o.x = f2bf(xv.x * (g * ((hv.x - mu) * rstd * wv.x + bv.x) + be));
    o.y = f2bf(xv.y * (g * ((hv.y - mu) * rstd * wv.y + bv.y) + be));
    o.z = f2bf(xv.z * (g * ((hv.z - mu) * rstd * wv.z + bv.z) + be));
    o.w = f2bf(xv.w * (g * ((hv.w - mu) * rstd * wv.w + bv.w) + be));
    *(us4*)(out_bf + (size_t)row * D_ + t * 4) = o;
    if (xcopy) ((float4*)(xcopy + (size_t)row * D_))[t] = xv;
}

// ---------------------------------------------------------------------------
// Tiled transpose + fp32->bf16: in [K][N] fp32 -> out [N][K] bf16
// ---------------------------------------------------------------------------
__global__ __launch_bounds__(256) void transpose_bf16_kernel(
    const float* __restrict__ in, unsigned short* __restrict__ out, int K, int N)
{
    __shared__ float tile[32][33];
    int n0 = blockIdx.x * 32, k0 = blockIdx.y * 32;
    int tx = threadIdx.x, ty = threadIdx.y;   // 32 x 8
    #pragma unroll
    for (int r = 0; r < 4; r++)
        tile[ty + r * 8][tx] = in[(size_t)(k0 + ty + r * 8) * N + n0 + tx];
    __syncthreads();
    #pragma unroll
    for (int r = 0; r < 4; r++)
        out[(size_t)(n0 + ty + r * 8) * K + k0 + tx] = f2bf(tile[tx][ty + r * 8]);
}

__global__ void concat_bias_kernel(const float* __restrict__ bq, const float* __restrict__ bk,
                                   const float* __restrict__ bv, float* __restrict__ outb)
{
    int i = blockIdx.x * 256 + threadIdx.x;
    if (i >= QKVW) return;
    float v = (i < 768) ? bq[i] : (i < 1536) ? bk[i - 768] : bv[i - 1536];
    outb[i] = v;
}

// ---------------------------------------------------------------------------
// bf16 MFMA GEMM (m97-style): C[M,N] = A[M,K] @ Bt[N,K]^T + bias (+relu)(+resid)
// ---------------------------------------------------------------------------
template<int OUT_BF16, int RELU>
__global__ __launch_bounds__(256) void gemm_mfma_kernel(
    const unsigned short* __restrict__ A, const unsigned short* __restrict__ Bt,
    const float* __restrict__ bias, const float* __restrict__ resid,
    void* __restrict__ Cout, int M, int N, int K)
{
    __shared__ unsigned short Asm[128 * 32];
    __shared__ unsigned short Bsm[128 * 32];

    int t = threadIdx.x;
    int lane = t & 63, wv = t >> 6;
    int wm = wv & 1, wn = wv >> 1;
    int l16 = lane & 15, quad = lane >> 4;

    int bm = blockIdx.x * 128;
    int bn = blockIdx.y * 128;

    const unsigned short* Abase = A  + (size_t)bm * K;
    const unsigned short* Bbase = Bt + (size_t)bn * K;

    int fl0 = t, fl1 = 256 + t;
    int r0s = fl0 >> 2, kc0 = (fl0 & 3) << 3;
    int r1s = fl1 >> 2, kc1 = (fl1 & 3) << 3;

    f4 acc[4][4] = {};

    for (int k0 = 0; k0 < K; k0 += 32) {
        __syncthreads();
        GLOBAL_LOAD_LDS16(Abase + (size_t)r0s * K + k0 + kc0, &Asm[fl0 * 8]);
        GLOBAL_LOAD_LDS16(Abase + (size_t)r1s * K + k0 + kc1, &Asm[fl1 * 8]);
        GLOBAL_LOAD_LDS16(Bbase + (size_t)r0s * K + k0 + kc0, &Bsm[fl0 * 8]);
        GLOBAL_LOAD_LDS16(Bbase + (size_t)r1s * K + k0 + kc1, &Bsm[fl1 * 8]);
        __syncthreads();

        bf16x8 af[4], bf[4];
        #pragma unroll
        for (int i = 0; i < 4; i++) {
            int m = wm * 64 + i * 16 + l16;
            af[i] = __builtin_bit_cast(bf16x8, *(const i4*)&Asm[m * 32 + quad * 8]);
        }
        #pragma unroll
        for (int j = 0; j < 4; j++) {
            int n = wn * 64 + j * 16 + l16;
            bf[j] = __builtin_bit_cast(bf16x8, *(const i4*)&Bsm[n * 32 + quad * 8]);
        }
        #pragma unroll
        for (int i = 0; i < 4; i++)
            #pragma unroll
            for (int j = 0; j < 4; j++)
                acc[i][j] = __builtin_amdgcn_mfma_f32_16x16x32_bf16(af[i], bf[j], acc[i][j], 0, 0, 0);
    }

    #pragma unroll
    for (int j = 0; j < 4; j++) {
        int colg = bn + wn * 64 + j * 16 + l16;
        float bv = bias ? bias[colg] : 0.f;
        #pragma unroll
        for (int i = 0; i < 4; i++) {
            #pragma unroll
            for (int r = 0; r < 4; r++) {
                int rowg = bm + wm * 64 + i * 16 + quad * 4 + r;
                float v = acc[i][j][r] + bv;
                if (RELU) v = fmaxf(v, 0.f);
                if (resid) v += resid[(size_t)rowg * N + colg];
                if (OUT_BF16)
                    ((unsigned short*)Cout)[(size_t)rowg * N + colg] = f2bf(v);
                else
                    ((float*)Cout)[(size_t)rowg * N + colg] = v;
            }
        }
    }
}

// ---------------------------------------------------------------------------
// q2/k2 norms from fused qkv bf16 buffer [NTOK][2304] -> q2g,k2g [B*H*S] fp32
// ---------------------------------------------------------------------------
__global__ __launch_bounds__(256) void norms_kernel(
    const unsigned short* __restrict__ qkv, float* __restrict__ q2g, float* __restrict__ k2g)
{
    int row = blockIdx.x;
    int t = threadIdx.x;
    int hh = t >> 5, l32 = t & 31;
    const unsigned short* base = qkv + (size_t)row * QKVW + hh * DH_ + l32 * 3;
    float qs = 0.f, ks = 0.f;
    #pragma unroll
    for (int e = 0; e < 3; e++) {
        float qv = bf2f(base[e]);
        float kv = bf2f(base[768 + e]);
        qs += qv * qv; ks += kv * kv;
    }
    #pragma unroll
    for (int off = 16; off > 0; off >>= 1) {
        qs += __shfl_xor(qs, off, 32);
        ks += __shfl_xor(ks, off, 32);
    }
    if (l32 == 0) {
        int b = row >> 10, s = row & 1023;
        int idx = (b * H_ + hh) * S_ + s;
        q2g[idx] = qs; k2g[idx] = ks;
    }
}

// ---------------------------------------------------------------------------
// V transpose into padded tiles: qkv V-part -> vt[(bh*16+kt)] tile of [96][72] bf16
// (tile stride 7168 shorts = 14336 B; pad cols 64..71 are garbage, never read)
// ---------------------------------------------------------------------------
__global__ __launch_bounds__(256) void vtrans_kernel(
    const unsigned short* __restrict__ qkv, unsigned short* __restrict__ vt)
{
    __shared__ unsigned short Vl[64][100];
    int blk = blockIdx.x;          // bh*16 + kt
    int bh = blk >> 4, kt = blk & 15;
    int b = bh >> 3, hh = bh & 7;
    int t = threadIdx.x;
    int key = t >> 2, qc = t & 3;
    const unsigned short* src = qkv + ((size_t)(b * S_ + kt * 64 + key)) * QKVW + 1536 + hh * DH_;
    #pragma unroll
    for (int i = 0; i < 3; i++) {
        int chunk = qc + i * 4;            // 0..11, 8 shorts each
        us8 v = *(const us8*)(src + chunk * 8);
        #pragma unroll
        for (int e = 0; e < 8; e++) Vl[key][chunk * 8 + e] = v[e];
    }
    __syncthreads();
    unsigned short* dst = vt + (size_t)blk * 7168;
    #pragma unroll
    for (int r = 0; r < 3; r++) {
        int c = r * 256 + t;               // 0..767
        int vd = c >> 3, kc = c & 7;
        us8 o;
        #pragma unroll
        for (int j = 0; j < 8; j++) o[j] = Vl[kc * 8 + j][vd];
        *(us8*)(dst + vd * 72 + kc * 8) = o;
    }
}

// ---------------------------------------------------------------------------
// MFMA flash attention with L2 distances.
// grid = 64 heads * 8 qtiles = 512 blocks; 4 waves; wave = 32 q-rows; TK=64.
// S^T = K.Q^T (A=K rows, B=Q rows); softmax intra-lane+shfl; P^T packed ->
// LDS b64; O = P.V with V from pre-transposed padded tiles.
// ---------------------------------------------------------------------------
__global__ __launch_bounds__(256, 2) void attn_mfma_kernel(
    const unsigned short* __restrict__ qkv,
    const unsigned short* __restrict__ vt,
    const float* __restrict__ q2g, const float* __restrict__ k2g,
    unsigned short* __restrict__ outb)
{
    __shared__ unsigned short Klds[64 * 96];     // [key][d]
    __shared__ unsigned short Vlds[7168];        // [vdim][72] + staging pad
    __shared__ unsigned short Plds[4][32 * 72];  // per-wave [qrow][key], stride 72

    int t = threadIdx.x;
    int lane = t & 63, w = t >> 6;
    int l16 = lane & 15, quad = lane >> 4;

    int bh = blockIdx.x >> 3;
    int qt = blockIdx.x & 7;
    int b = bh >> 3, hh = bh & 7;

    int qrow0 = qt * 128 + w * 32;

    const unsigned short* qb = qkv + ((size_t)(b * S_ + qrow0)) * QKVW + hh * DH_;
    bf16x8 qf[2][3];
    #pragma unroll
    for (int n = 0; n < 2; n++)
        #pragma unroll
        for (int d = 0; d < 3; d++)
            qf[n][d] = __builtin_bit_cast(bf16x8,
                *(const i4*)(qb + (size_t)(n * 16 + l16) * QKVW + d * 32 + quad * 8));

    float q2n[2];
    q2n[0] = q2g[bh * S_ + qrow0 + l16];
    q2n[1] = q2g[bh * S_ + qrow0 + 16 + l16];

    float mrun[2] = {-INFINITY, -INFINITY};
    float lrun[2] = {0.f, 0.f};
    f4 Oacc[2][6] = {};

    const float rs = 0.10206207261596575f;   // 1/sqrt(96)

    const unsigned short* kgb = qkv + ((size_t)(b * S_)) * QKVW + 768 + hh * DH_;
    const unsigned short* vgb0 = vt + (size_t)(bh * 16) * 7168;

    for (int it = 0; it < 16; it++) {
        __syncthreads();
        // stage K tile [64][96]: 768 16B chunks
        #pragma unroll
        for (int r = 0; r < 3; r++) {
            int c = r * 256 + t;
            int key = c / 12, dc = c % 12;
            GLOBAL_LOAD_LDS16(kgb + ((size_t)(it * 64 + key)) * QKVW + dc * 8, &Klds[c * 8]);
        }
        // stage Vt tile: 14336 B = 896 chunks
        const unsigned short* vgb = vgb0 + (size_t)it * 7168;
        #pragma unroll
        for (int r = 0; r < 3; r++)
            GLOBAL_LOAD_LDS16(vgb + (r * 256 + t) * 8, &Vlds[(r * 256 + t) * 8]);
        if (t < 128)
            GLOBAL_LOAD_LDS16(vgb + (768 + t) * 8, &Vlds[(768 + t) * 8]);
        __syncthreads();

        // S^T = K . Q^T   (sf[ktile][qntile], C-frag: col=qrow(l16), row=key(quad*4+r))
        f4 sf[4][2];
        #pragma unroll
        for (int kt2 = 0; kt2 < 4; kt2++) {
            bf16x8 kf[3];
            #pragma unroll
            for (int d = 0; d < 3; d++)
                kf[d] = __builtin_bit_cast(bf16x8,
                    *(const i4*)&Klds[(kt2 * 16 + l16) * 96 + d * 32 + quad * 8]);
            #pragma unroll
            for (int n = 0; n < 2; n++) {
                f4 a = {};
                #pragma unroll
                for (int d = 0; d < 3; d++)
                    a = __builtin_amdgcn_mfma_f32_16x16x32_bf16(kf[d], qf[n][d], a, 0, 0, 0);
                sf[kt2][n] = a;
            }
        }
        // scores: -sqrt(max(q2+k2-2qk,0))/sqrt(DH)
        #pragma unroll
        for (int kt2 = 0; kt2 < 4; kt2++) {
            float4 k2f = *(const float4*)(k2g + bh * S_ + it * 64 + kt2 * 16 + quad * 4);
            float k2a[4] = {k2f.x, k2f.y, k2f.z, k2f.w};
            #pragma unroll
            for (int n = 0; n < 2; n++) {
                f4 s = sf[kt2][n];
                #pragma unroll
                for (int r2 = 0; r2 < 4; r2++) {
                    float d2 = fmaxf(q2n[n] + k2a[r2] - 2.f * s[r2], 0.f);
                    s[r2] = -sqrtf(d2) * rs;
                }
                sf[kt2][n] = s;
            }
        }
        // online softmax per q-ntile + pack P into LDS
        float alph[2];
        #pragma unroll
        for (int n = 0; n < 2; n++) {
            f4 m4 = sf[0][n];
            #pragma unroll
            for (int kt2 = 1; kt2 < 4; kt2++)
                #pragma unroll
                for (int r2 = 0; r2 < 4; r2++)
                    m4[r2] = fmaxf(m4[r2], sf[kt2][n][r2]);
            float mx = fmaxf(fmaxf(m4[0], m4[1]), fmaxf(m4[2], m4[3]));
            mx = fmaxf(mx, __shfl_xor(mx, 16, 64));
            mx = fmaxf(mx, __shfl_xor(mx, 32, 64));
            float mnew = fmaxf(mrun[n], mx);
            alph[n] = __expf(mrun[n] - mnew);
            mrun[n] = mnew;
            float ssum = 0.f;
            #pragma unroll
            for (int kt2 = 0; kt2 < 4; kt2++) {
                f4 s = sf[kt2][n];
                #pragma unroll
                for (int r2 = 0; r2 < 4; r2++) { s[r2] = __expf(s[r2] - mnew); ssum += s[r2]; }
                sf[kt2][n] = s;
            }
            ssum += __shfl_xor(ssum, 16, 64);
            ssum += __shfl_xor(ssum, 32, 64);
            lrun[n] = lrun[n] * alph[n] + ssum;
            #pragma unroll
            for (int kt2 = 0; kt2 < 4; kt2++) {
                f4 s = sf[kt2][n];
                uint2 pk;
                pk.x = (unsigned)f2bf(s[0]) | ((unsigned)f2bf(s[1]) << 16);
                pk.y = (unsigned)f2bf(s[2]) | ((unsigned)f2bf(s[3]) << 16);
                *(uint2*)&Plds[w][(n * 16 + l16) * 72 + kt2 * 16 + quad * 4] = pk;
            }
        }
        // rescale O by alpha (broadcast to C-layout rows)
        f4 av0, av1;
        #pragma unroll
        for (int r2 = 0; r2 < 4; r2++) {
            int src = quad * 4 + r2;
            av0[r2] = __shfl(alph[0], src, 64);
            av1[r2] = __shfl(alph[1], src, 64);
        }
        #pragma unroll
        for (int vtl = 0; vtl < 6; vtl++)
            #pragma unroll
            for (int r2 = 0; r2 < 4; r2++) {
                Oacc[0][vtl][r2] *= av0[r2];
                Oacc[1][vtl][r2] *= av1[r2];
            }
        // O += P . V
        bf16x8 pa[2][2];
        #pragma unroll
        for (int mt = 0; mt < 2; mt++)
            #pragma unroll
            for (int kf2 = 0; kf2 < 2; kf2++)
                pa[mt][kf2] = __builtin_bit_cast(bf16x8,
                    *(const i4*)&Plds[w][(mt * 16 + l16) * 72 + kf2 * 32 + quad * 8]);
        #pragma unroll
        for (int vtl = 0; vtl < 6; vtl++) {
            bf16x8 vf0 = __builtin_bit_cast(bf16x8,
                *(const i4*)&Vlds[(vtl * 16 + l16) * 72 + quad * 8]);
            bf16x8 vf1 = __builtin_bit_cast(bf16x8,
                *(const i4*)&Vlds[(vtl * 16 + l16) * 72 + 32 + quad * 8]);
            #pragma unroll
            for (int mt = 0; mt < 2; mt++) {
                Oacc[mt][vtl] = __builtin_amdgcn_mfma_f32_16x16x32_bf16(pa[mt][0], vf0, Oacc[mt][vtl], 0, 0, 0);
                Oacc[mt][vtl] = __builtin_amdgcn_mfma_f32_16x16x32_bf16(pa[mt][1], vf1, Oacc[mt][vtl], 0, 0, 0);
            }
        }
    }
    // epilogue: scale by 1/l, store bf16
    float inv0 = 1.f / lrun[0], inv1 = 1.f / lrun[1];
    f4 iv0, iv1;
    #pragma unroll
    for (int r2 = 0; r2 < 4; r2++) {
        int src = quad * 4 + r2;
        iv0[r2] = __shfl(inv0, src, 64);
        iv1[r2] = __shfl(inv1, src, 64);
    }
    #pragma unroll
    for (int mt = 0; mt < 2; mt++)
        #pragma unroll
        for (int vtl = 0; vtl < 6; vtl++)
            #pragma unroll
            for (int r2 = 0; r2 < 4; r2++) {
                int row = b * S_ + qrow0 + mt * 16 + quad * 4 + r2;
                float v = Oacc[mt][vtl][r2] * (mt == 0 ? iv0[r2] : iv1[r2]);
                outb[(size_t)row * D_ + hh * DH_ + vtl * 16 + l16] = f2bf(v);
            }
}

// ---------------------------------------------------------------------------
extern "C" void kernel_launch(void* const* d_in, const int* in_sizes, int n_in,
                              void* d_out, int out_size, void* d_ws, size_t ws_size,
                              hipStream_t stream)
{
    const float* h    = (const float*)d_in[0];
    const float* x    = (const float*)d_in[1];
    const float* g1   = (const float*)d_in[2];
    const float* be1  = (const float*)d_in[3];
    const float* ln1w = (const float*)d_in[4];
    const float* ln1b = (const float*)d_in[5];
    const float* g2   = (const float*)d_in[6];
    const float* be2  = (const float*)d_in[7];
    const float* ln2w = (const float*)d_in[8];
    const float* ln2b = (const float*)d_in[9];
    const float* Wq   = (const float*)d_in[10];
    const float* bq   = (const float*)d_in[11];
    const float* Wk   = (const float*)d_in[12];
    const float* bk   = (const float*)d_in[13];
    const float* Wv   = (const float*)d_in[14];
    const float* bv   = (const float*)d_in[15];
    const float* Wo   = (const float*)d_in[16];
    const float* bo   = (const float*)d_in[17];
    const float* W1   = (const float*)d_in[18];
    const float* b1   = (const float*)d_in[19];
    const float* W2   = (const float*)d_in[20];
    const float* b2   = (const float*)d_in[21];

    float* out = (float*)d_out;
    char* wsb = (char*)d_ws;
    const size_t ND = (size_t)NTOK * D_;

    // workspace layout (bytes)
    unsigned short* Wqkvt = (unsigned short*)(wsb);                       // [2304][768]
    unsigned short* Wot   = (unsigned short*)(wsb + 3538944);             // [768][768]
    unsigned short* W1t   = (unsigned short*)(wsb + 3538944 + 1179648);   // [3072][768]
    unsigned short* W2t   = (unsigned short*)(wsb + 3538944 + 1179648 + 4718592); // [768][3072]
    size_t off = 3538944 + 1179648 + 4718592 + 4718592;
    float* bqkv = (float*)(wsb + off);            off += 16384;
    unsigned short* h1b   = (unsigned short*)(wsb + off); off += ND * 2;   // alias: attnb
    unsigned short* qkvb  = (unsigned short*)(wsb + off); off += (size_t)NTOK * QKVW * 2;
    float* q2g  = (float*)(wsb + off);            off += (size_t)B_ * H_ * S_ * 4;
    float* k2g  = (float*)(wsb + off);            off += (size_t)B_ * H_ * S_ * 4;
    float* htmp = (float*)(wsb + off);            off += ND * 4;
    unsigned short* vtg = (unsigned short*)(wsb + off); off += (size_t)1024 * 14336;
    unsigned short* attnb   = h1b;                         // h1b dead after QKV GEMM
    unsigned short* h2b     = qkvb;                        // qkvb dead after attention
    unsigned short* hiddenb = qkvb + ND;                   // chunk [4096][3072] bf16

    // --- weight prep (transpose + bf16) ---
    dim3 tb(32, 8);
    transpose_bf16_kernel<<<dim3(768/32, 768/32), tb, 0, stream>>>(Wq, Wqkvt,              768, 768);
    transpose_bf16_kernel<<<dim3(768/32, 768/32), tb, 0, stream>>>(Wk, Wqkvt + 768*768,    768, 768);
    transpose_bf16_kernel<<<dim3(768/32, 768/32), tb, 0, stream>>>(Wv, Wqkvt + 2*768*768,  768, 768);
    transpose_bf16_kernel<<<dim3(768/32, 768/32), tb, 0, stream>>>(Wo, Wot, 768, 768);
    transpose_bf16_kernel<<<dim3(3072/32, 768/32), tb, 0, stream>>>(W1, W1t, 768, 3072);
    transpose_bf16_kernel<<<dim3(768/32, 3072/32), tb, 0, stream>>>(W2, W2t, 3072, 768);
    concat_bias_kernel<<<9, 256, 0, stream>>>(bq, bk, bv, bqkv);

    // 1. SLN1 -> h1b (bf16), copy x -> out[0:ND]
    sln_kernel<<<NTOK, 192, 0, stream>>>(h, x, g1, be1, ln1w, ln1b, h1b, out);

    // 2. fused QKV GEMM: [8192,768] @ [768,2304] -> qkvb bf16
    gemm_mfma_kernel<1, 0><<<dim3(NTOK/128, QKVW/128), 256, 0, stream>>>(
        h1b, Wqkvt, bqkv, nullptr, qkvb, NTOK, QKVW, D_);

    // 3. norms + V transpose tiles
    norms_kernel<<<NTOK, 256, 0, stream>>>(qkvb, q2g, k2g);
    vtrans_kernel<<<1024, 256, 0, stream>>>(qkvb, vtg);

    // 4. MFMA attention -> attnb bf16
    attn_mfma_kernel<<<512, 256, 0, stream>>>(qkvb, vtg, q2g, k2g, attnb);

    // 5. Wo projection + residual h -> htmp fp32
    gemm_mfma_kernel<0, 0><<<dim3(NTOK/128, D_/128), 256, 0, stream>>>(
        attnb, Wot, bo, h, htmp, NTOK, D_, D_);

    // 6. SLN2 -> h2b bf16
    sln_kernel<<<NTOK, 192, 0, stream>>>(htmp, x, g2, be2, ln2w, ln2b, h2b, nullptr);

    // 7. MLP in 2 row-chunks of 4096
    for (int r0 = 0; r0 < NTOK; r0 += 4096) {
        gemm_mfma_kernel<1, 1><<<dim3(4096/128, DFF_/128), 256, 0, stream>>>(
            h2b + (size_t)r0 * D_, W1t, b1, nullptr, hiddenb, 4096, DFF_, D_);
        gemm_mfma_kernel<0, 0><<<dim3(4096/128, D_/128), 256, 0, stream>>>(
            hiddenb, W2t, b2, htmp + (size_t)r0 * D_, out + ND + (size_t)r0 * D_, 4096, D_, DFF_);
    }
    (void)in_sizes; (void)n_in; (void)out_size; (void)ws_size;
}

// Round 4
// 501.311 us; speedup vs baseline: 6.3234x; 1.2628x over previous
//
#include <hip/hip_runtime.h>
#include <math.h>

#define B_ 8
#define S_ 1024
#define D_ 768
#define H_ 8
#define DH_ 96
#define DFF_ 3072
#define NTOK (B_*S_)
#define QKVW 2304            // fused q|k|v width
#define EPS_ 1e-5f

typedef __attribute__((ext_vector_type(4))) float f4;
typedef __attribute__((ext_vector_type(4))) int i4;
typedef __attribute__((ext_vector_type(8))) __bf16 bf16x8;
typedef __attribute__((ext_vector_type(4))) unsigned short us4;
typedef __attribute__((ext_vector_type(8))) unsigned short us8;

static __device__ __forceinline__ unsigned short f2bf(float f) {
    unsigned int u = __builtin_bit_cast(unsigned int, f);
    u += 0x7fffu + ((u >> 16) & 1u);
    return (unsigned short)(u >> 16);
}
static __device__ __forceinline__ float bf2f(unsigned short u) {
    unsigned int x = ((unsigned int)u) << 16;
    return __builtin_bit_cast(float, x);
}

#define GLOBAL_LOAD_LDS16(g, l) \
    __builtin_amdgcn_global_load_lds((const __attribute__((address_space(1))) unsigned int*)(g), \
                                     (__attribute__((address_space(3))) unsigned int*)(l), 16, 0, 0)

// ---------------------------------------------------------------------------
// SLN: out_bf16 = bf16( x * (gamma * LayerNorm(h) + beta) ); optional x copy (fp32)
// ---------------------------------------------------------------------------
__global__ __launch_bounds__(192) void sln_kernel(
    const float* __restrict__ h, const float* __restrict__ x,
    const float* __restrict__ gamma, const float* __restrict__ beta,
    const float* __restrict__ w, const float* __restrict__ bvec,
    unsigned short* __restrict__ out_bf, float* __restrict__ xcopy)
{
    int row = blockIdx.x;
    int t = threadIdx.x;
    const float4* h4 = (const float4*)(h + (size_t)row * D_);
    const float4* x4 = (const float4*)(x + (size_t)row * D_);
    float4 hv = h4[t];
    float s  = hv.x + hv.y + hv.z + hv.w;
    float ss = hv.x*hv.x + hv.y*hv.y + hv.z*hv.z + hv.w*hv.w;
    #pragma unroll
    for (int off = 32; off > 0; off >>= 1) {
        s  += __shfl_down(s, off);
        ss += __shfl_down(ss, off);
    }
    __shared__ float red[2][3];
    int wid = t >> 6;
    if ((t & 63) == 0) { red[0][wid] = s; red[1][wid] = ss; }
    __syncthreads();
    float sum   = red[0][0] + red[0][1] + red[0][2];
    float sumsq = red[1][0] + red[1][1] + red[1][2];
    float mu  = sum * (1.0f / D_);
    float var = sumsq * (1.0f / D_) - mu * mu;
    float rstd = rsqrtf(var + EPS_);
    float g = gamma[0], be = beta[0];
    float4 wv = ((const float4*)w)[t];
    float4 bv = ((const float4*)bvec)[t];
    float4 xv = x4[t];
    us4 o;
    o.x = f2bf(xv.x * (g * ((hv.x - mu) * rstd * wv.x + bv.x) + be));
    o.y = f2bf(xv.y * (g * ((hv.y - mu) * rstd * wv.y + bv.y) + be));
    o.z = f2bf(xv.z * (g * ((hv.z - mu) * rstd * wv.z + bv.z) + be));
    o.w = f2bf(xv.w * (g * ((hv.w - mu) * rstd * wv.w + bv.w) + be));
    *(us4*)(out_bf + (size_t)row * D_ + t * 4) = o;
    if (xcopy) ((float4*)(xcopy + (size_t)row * D_))[t] = xv;
}

// ---------------------------------------------------------------------------
// Tiled transpose + fp32->bf16: in [K][N] fp32 -> out [N][K] bf16
// ---------------------------------------------------------------------------
__global__ __launch_bounds__(256) void transpose_bf16_kernel(
    const float* __restrict__ in, unsigned short* __restrict__ out, int K, int N)
{
    __shared__ float tile[32][33];
    int n0 = blockIdx.x * 32, k0 = blockIdx.y * 32;
    int tx = threadIdx.x, ty = threadIdx.y;   // 32 x 8
    #pragma unroll
    for (int r = 0; r < 4; r++)
        tile[ty + r * 8][tx] = in[(size_t)(k0 + ty + r * 8) * N + n0 + tx];
    __syncthreads();
    #pragma unroll
    for (int r = 0; r < 4; r++)
        out[(size_t)(n0 + ty + r * 8) * K + k0 + tx] = f2bf(tile[tx][ty + r * 8]);
}

__global__ void concat_bias_kernel(const float* __restrict__ bq, const float* __restrict__ bk,
                                   const float* __restrict__ bv, float* __restrict__ outb)
{
    int i = blockIdx.x * 256 + threadIdx.x;
    if (i >= QKVW) return;
    float v = (i < 768) ? bq[i] : (i < 1536) ? bk[i - 768] : bv[i - 1536];
    outb[i] = v;
}

// ---------------------------------------------------------------------------
// bf16 MFMA GEMM, operand-swapped for vectorized epilogue:
// C[M,N] = A[M,K] @ Bt[N,K]^T + bias (+relu)(+resid)
// A-frag = weight rows (Bt), B-frag = activation rows (A) =>
// C-frag: col(l16) = C row, row(quad*4+r) = 4 consecutive C cols => float4 stores.
// ---------------------------------------------------------------------------
template<int OUT_BF16, int RELU>
__global__ __launch_bounds__(256) void gemm_mfma_kernel(
    const unsigned short* __restrict__ A, const unsigned short* __restrict__ Bt,
    const float* __restrict__ bias, const float* __restrict__ resid,
    void* __restrict__ Cout, int M, int N, int K)
{
    __shared__ unsigned short Asm[128 * 32];
    __shared__ unsigned short Bsm[128 * 32];

    int t = threadIdx.x;
    int lane = t & 63, wv = t >> 6;
    int wm = wv & 1, wn = wv >> 1;
    int l16 = lane & 15, quad = lane >> 4;

    int bm = blockIdx.x * 128;
    int bn = blockIdx.y * 128;

    const unsigned short* Abase = A  + (size_t)bm * K;
    const unsigned short* Bbase = Bt + (size_t)bn * K;

    int fl0 = t, fl1 = 256 + t;
    int r0s = fl0 >> 2, kc0 = (fl0 & 3) << 3;
    int r1s = fl1 >> 2, kc1 = (fl1 & 3) << 3;

    f4 acc[4][4] = {};   // acc[j][i]: j = weight (col) tile, i = act (row) tile

    for (int k0 = 0; k0 < K; k0 += 32) {
        __syncthreads();
        GLOBAL_LOAD_LDS16(Abase + (size_t)r0s * K + k0 + kc0, &Asm[fl0 * 8]);
        GLOBAL_LOAD_LDS16(Abase + (size_t)r1s * K + k0 + kc1, &Asm[fl1 * 8]);
        GLOBAL_LOAD_LDS16(Bbase + (size_t)r0s * K + k0 + kc0, &Bsm[fl0 * 8]);
        GLOBAL_LOAD_LDS16(Bbase + (size_t)r1s * K + k0 + kc1, &Bsm[fl1 * 8]);
        __syncthreads();

        bf16x8 xf[4], wf[4];
        #pragma unroll
        for (int i = 0; i < 4; i++) {
            int m = wm * 64 + i * 16 + l16;
            xf[i] = __builtin_bit_cast(bf16x8, *(const i4*)&Asm[m * 32 + quad * 8]);
        }
        #pragma unroll
        for (int j = 0; j < 4; j++) {
            int n = wn * 64 + j * 16 + l16;
            wf[j] = __builtin_bit_cast(bf16x8, *(const i4*)&Bsm[n * 32 + quad * 8]);
        }
        #pragma unroll
        for (int j = 0; j < 4; j++)
            #pragma unroll
            for (int i = 0; i < 4; i++)
                acc[j][i] = __builtin_amdgcn_mfma_f32_16x16x32_bf16(wf[j], xf[i], acc[j][i], 0, 0, 0);
    }

    // vectorized epilogue: each lane owns row (i*16+l16), 4 consecutive cols per (j,quad)
    #pragma unroll
    for (int i = 0; i < 4; i++) {
        int rowg = bm + wm * 64 + i * 16 + l16;
        #pragma unroll
        for (int j = 0; j < 4; j++) {
            int colg0 = bn + wn * 64 + j * 16 + quad * 4;
            f4 v = acc[j][i];
            f4 b4 = *(const f4*)&bias[colg0];
            v += b4;
            if (RELU) {
                #pragma unroll
                for (int r = 0; r < 4; r++) v[r] = fmaxf(v[r], 0.f);
            }
            if (resid) {
                f4 r4 = *(const f4*)&resid[(size_t)rowg * N + colg0];
                v += r4;
            }
            if (OUT_BF16) {
                us4 o;
                o.x = f2bf(v[0]); o.y = f2bf(v[1]); o.z = f2bf(v[2]); o.w = f2bf(v[3]);
                *(us4*)((unsigned short*)Cout + (size_t)rowg * N + colg0) = o;
            } else {
                *(f4*)((float*)Cout + (size_t)rowg * N + colg0) = v;
            }
        }
    }
}

// ---------------------------------------------------------------------------
// q2/k2 norms from fused qkv bf16 buffer [NTOK][2304] -> q2g,k2g [B*H*S] fp32
// ---------------------------------------------------------------------------
__global__ __launch_bounds__(256) void norms_kernel(
    const unsigned short* __restrict__ qkv, float* __restrict__ q2g, float* __restrict__ k2g)
{
    int row = blockIdx.x;
    int t = threadIdx.x;
    int hh = t >> 5, l32 = t & 31;
    const unsigned short* base = qkv + (size_t)row * QKVW + hh * DH_ + l32 * 3;
    float qs = 0.f, ks = 0.f;
    #pragma unroll
    for (int e = 0; e < 3; e++) {
        float qv = bf2f(base[e]);
        float kv = bf2f(base[768 + e]);
        qs += qv * qv; ks += kv * kv;
    }
    #pragma unroll
    for (int off = 16; off > 0; off >>= 1) {
        qs += __shfl_xor(qs, off, 32);
        ks += __shfl_xor(ks, off, 32);
    }
    if (l32 == 0) {
        int b = row >> 10, s = row & 1023;
        int idx = (b * H_ + hh) * S_ + s;
        q2g[idx] = qs; k2g[idx] = ks;
    }
}

// ---------------------------------------------------------------------------
// V transpose into padded tiles: qkv V-part -> vt[(bh*16+kt)] tile of [96][72] bf16
// ---------------------------------------------------------------------------
__global__ __launch_bounds__(256) void vtrans_kernel(
    const unsigned short* __restrict__ qkv, unsigned short* __restrict__ vt)
{
    __shared__ unsigned short Vl[64][100];
    int blk = blockIdx.x;          // bh*16 + kt
    int bh = blk >> 4, kt = blk & 15;
    int b = bh >> 3, hh = bh & 7;
    int t = threadIdx.x;
    int key = t >> 2, qc = t & 3;
    const unsigned short* src = qkv + ((size_t)(b * S_ + kt * 64 + key)) * QKVW + 1536 + hh * DH_;
    #pragma unroll
    for (int i = 0; i < 3; i++) {
        int chunk = qc + i * 4;            // 0..11, 8 shorts each
        us8 v = *(const us8*)(src + chunk * 8);
        #pragma unroll
        for (int e = 0; e < 8; e++) Vl[key][chunk * 8 + e] = v[e];
    }
    __syncthreads();
    unsigned short* dst = vt + (size_t)blk * 7168;
    #pragma unroll
    for (int r = 0; r < 3; r++) {
        int c = r * 256 + t;               // 0..767
        int vd = c >> 3, kc = c & 7;
        us8 o;
        #pragma unroll
        for (int j = 0; j < 8; j++) o[j] = Vl[kc * 8 + j][vd];
        *(us8*)(dst + vd * 72 + kc * 8) = o;
    }
}

// ---------------------------------------------------------------------------
// MFMA flash attention with L2 distances (unchanged from round 3).
// ---------------------------------------------------------------------------
__global__ __launch_bounds__(256, 2) void attn_mfma_kernel(
    const unsigned short* __restrict__ qkv,
    const unsigned short* __restrict__ vt,
    const float* __restrict__ q2g, const float* __restrict__ k2g,
    unsigned short* __restrict__ outb)
{
    __shared__ unsigned short Klds[64 * 96];     // [key][d]
    __shared__ unsigned short Vlds[7168];        // [vdim][72] + staging pad
    __shared__ unsigned short Plds[4][32 * 72];  // per-wave [qrow][key], stride 72

    int t = threadIdx.x;
    int lane = t & 63, w = t >> 6;
    int l16 = lane & 15, quad = lane >> 4;

    int bh = blockIdx.x >> 3;
    int qt = blockIdx.x & 7;
    int b = bh >> 3, hh = bh & 7;

    int qrow0 = qt * 128 + w * 32;

    const unsigned short* qb = qkv + ((size_t)(b * S_ + qrow0)) * QKVW + hh * DH_;
    bf16x8 qf[2][3];
    #pragma unroll
    for (int n = 0; n < 2; n++)
        #pragma unroll
        for (int d = 0; d < 3; d++)
            qf[n][d] = __builtin_bit_cast(bf16x8,
                *(const i4*)(qb + (size_t)(n * 16 + l16) * QKVW + d * 32 + quad * 8));

    float q2n[2];
    q2n[0] = q2g[bh * S_ + qrow0 + l16];
    q2n[1] = q2g[bh * S_ + qrow0 + 16 + l16];

    float mrun[2] = {-INFINITY, -INFINITY};
    float lrun[2] = {0.f, 0.f};
    f4 Oacc[2][6] = {};

    const float rs = 0.10206207261596575f;   // 1/sqrt(96)

    const unsigned short* kgb = qkv + ((size_t)(b * S_)) * QKVW + 768 + hh * DH_;
    const unsigned short* vgb0 = vt + (size_t)(bh * 16) * 7168;

    for (int it = 0; it < 16; it++) {
        __syncthreads();
        #pragma unroll
        for (int r = 0; r < 3; r++) {
            int c = r * 256 + t;
            int key = c / 12, dc = c % 12;
            GLOBAL_LOAD_LDS16(kgb + ((size_t)(it * 64 + key)) * QKVW + dc * 8, &Klds[c * 8]);
        }
        const unsigned short* vgb = vgb0 + (size_t)it * 7168;
        #pragma unroll
        for (int r = 0; r < 3; r++)
            GLOBAL_LOAD_LDS16(vgb + (r * 256 + t) * 8, &Vlds[(r * 256 + t) * 8]);
        if (t < 128)
            GLOBAL_LOAD_LDS16(vgb + (768 + t) * 8, &Vlds[(768 + t) * 8]);
        __syncthreads();

        // S^T = K . Q^T
        f4 sf[4][2];
        #pragma unroll
        for (int kt2 = 0; kt2 < 4; kt2++) {
            bf16x8 kf[3];
            #pragma unroll
            for (int d = 0; d < 3; d++)
                kf[d] = __builtin_bit_cast(bf16x8,
                    *(const i4*)&Klds[(kt2 * 16 + l16) * 96 + d * 32 + quad * 8]);
            #pragma unroll
            for (int n = 0; n < 2; n++) {
                f4 a = {};
                #pragma unroll
                for (int d = 0; d < 3; d++)
                    a = __builtin_amdgcn_mfma_f32_16x16x32_bf16(kf[d], qf[n][d], a, 0, 0, 0);
                sf[kt2][n] = a;
            }
        }
        // scores
        #pragma unroll
        for (int kt2 = 0; kt2 < 4; kt2++) {
            float4 k2f = *(const float4*)(k2g + bh * S_ + it * 64 + kt2 * 16 + quad * 4);
            float k2a[4] = {k2f.x, k2f.y, k2f.z, k2f.w};
            #pragma unroll
            for (int n = 0; n < 2; n++) {
                f4 s = sf[kt2][n];
                #pragma unroll
                for (int r2 = 0; r2 < 4; r2++) {
                    float d2 = fmaxf(q2n[n] + k2a[r2] - 2.f * s[r2], 0.f);
                    s[r2] = -sqrtf(d2) * rs;
                }
                sf[kt2][n] = s;
            }
        }
        // online softmax + pack P
        float alph[2];
        #pragma unroll
        for (int n = 0; n < 2; n++) {
            f4 m4 = sf[0][n];
            #pragma unroll
            for (int kt2 = 1; kt2 < 4; kt2++)
                #pragma unroll
                for (int r2 = 0; r2 < 4; r2++)
                    m4[r2] = fmaxf(m4[r2], sf[kt2][n][r2]);
            float mx = fmaxf(fmaxf(m4[0], m4[1]), fmaxf(m4[2], m4[3]));
            mx = fmaxf(mx, __shfl_xor(mx, 16, 64));
            mx = fmaxf(mx, __shfl_xor(mx, 32, 64));
            float mnew = fmaxf(mrun[n], mx);
            alph[n] = __expf(mrun[n] - mnew);
            mrun[n] = mnew;
            float ssum = 0.f;
            #pragma unroll
            for (int kt2 = 0; kt2 < 4; kt2++) {
                f4 s = sf[kt2][n];
                #pragma unroll
                for (int r2 = 0; r2 < 4; r2++) { s[r2] = __expf(s[r2] - mnew); ssum += s[r2]; }
                sf[kt2][n] = s;
            }
            ssum += __shfl_xor(ssum, 16, 64);
            ssum += __shfl_xor(ssum, 32, 64);
            lrun[n] = lrun[n] * alph[n] + ssum;
            #pragma unroll
            for (int kt2 = 0; kt2 < 4; kt2++) {
                f4 s = sf[kt2][n];
                uint2 pk;
                pk.x = (unsigned)f2bf(s[0]) | ((unsigned)f2bf(s[1]) << 16);
                pk.y = (unsigned)f2bf(s[2]) | ((unsigned)f2bf(s[3]) << 16);
                *(uint2*)&Plds[w][(n * 16 + l16) * 72 + kt2 * 16 + quad * 4] = pk;
            }
        }
        // rescale O
        f4 av0, av1;
        #pragma unroll
        for (int r2 = 0; r2 < 4; r2++) {
            int src = quad * 4 + r2;
            av0[r2] = __shfl(alph[0], src, 64);
            av1[r2] = __shfl(alph[1], src, 64);
        }
        #pragma unroll
        for (int vtl = 0; vtl < 6; vtl++)
            #pragma unroll
            for (int r2 = 0; r2 < 4; r2++) {
                Oacc[0][vtl][r2] *= av0[r2];
                Oacc[1][vtl][r2] *= av1[r2];
            }
        // O += P . V
        bf16x8 pa[2][2];
        #pragma unroll
        for (int mt = 0; mt < 2; mt++)
            #pragma unroll
            for (int kf2 = 0; kf2 < 2; kf2++)
                pa[mt][kf2] = __builtin_bit_cast(bf16x8,
                    *(const i4*)&Plds[w][(mt * 16 + l16) * 72 + kf2 * 32 + quad * 8]);
        #pragma unroll
        for (int vtl = 0; vtl < 6; vtl++) {
            bf16x8 vf0 = __builtin_bit_cast(bf16x8,
                *(const i4*)&Vlds[(vtl * 16 + l16) * 72 + quad * 8]);
            bf16x8 vf1 = __builtin_bit_cast(bf16x8,
                *(const i4*)&Vlds[(vtl * 16 + l16) * 72 + 32 + quad * 8]);
            #pragma unroll
            for (int mt = 0; mt < 2; mt++) {
                Oacc[mt][vtl] = __builtin_amdgcn_mfma_f32_16x16x32_bf16(pa[mt][0], vf0, Oacc[mt][vtl], 0, 0, 0);
                Oacc[mt][vtl] = __builtin_amdgcn_mfma_f32_16x16x32_bf16(pa[mt][1], vf1, Oacc[mt][vtl], 0, 0, 0);
            }
        }
    }
    float inv0 = 1.f / lrun[0], inv1 = 1.f / lrun[1];
    f4 iv0, iv1;
    #pragma unroll
    for (int r2 = 0; r2 < 4; r2++) {
        int src = quad * 4 + r2;
        iv0[r2] = __shfl(inv0, src, 64);
        iv1[r2] = __shfl(inv1, src, 64);
    }
    #pragma unroll
    for (int mt = 0; mt < 2; mt++)
        #pragma unroll
        for (int vtl = 0; vtl < 6; vtl++)
            #pragma unroll
            for (int r2 = 0; r2 < 4; r2++) {
                int row = b * S_ + qrow0 + mt * 16 + quad * 4 + r2;
                float v = Oacc[mt][vtl][r2] * (mt == 0 ? iv0[r2] : iv1[r2]);
                outb[(size_t)row * D_ + hh * DH_ + vtl * 16 + l16] = f2bf(v);
            }
}

// ---------------------------------------------------------------------------
extern "C" void kernel_launch(void* const* d_in, const int* in_sizes, int n_in,
                              void* d_out, int out_size, void* d_ws, size_t ws_size,
                              hipStream_t stream)
{
    const float* h    = (const float*)d_in[0];
    const float* x    = (const float*)d_in[1];
    const float* g1   = (const float*)d_in[2];
    const float* be1  = (const float*)d_in[3];
    const float* ln1w = (const float*)d_in[4];
    const float* ln1b = (const float*)d_in[5];
    const float* g2   = (const float*)d_in[6];
    const float* be2  = (const float*)d_in[7];
    const float* ln2w = (const float*)d_in[8];
    const float* ln2b = (const float*)d_in[9];
    const float* Wq   = (const float*)d_in[10];
    const float* bq   = (const float*)d_in[11];
    const float* Wk   = (const float*)d_in[12];
    const float* bk   = (const float*)d_in[13];
    const float* Wv   = (const float*)d_in[14];
    const float* bv   = (const float*)d_in[15];
    const float* Wo   = (const float*)d_in[16];
    const float* bo   = (const float*)d_in[17];
    const float* W1   = (const float*)d_in[18];
    const float* b1   = (const float*)d_in[19];
    const float* W2   = (const float*)d_in[20];
    const float* b2   = (const float*)d_in[21];

    float* out = (float*)d_out;
    char* wsb = (char*)d_ws;
    const size_t ND = (size_t)NTOK * D_;

    // workspace layout (bytes): persistent region first, dead-pool last so
    // the full-size MLP hidden (50.3 MB bf16) can overlay the dead pool.
    size_t off = 0;
    unsigned short* W1t = (unsigned short*)(wsb + off); off += 4718592;       // [3072][768]
    unsigned short* W2t = (unsigned short*)(wsb + off); off += 4718592;       // [768][3072]
    float* bqkv = (float*)(wsb + off);                  off += 16384;
    float* htmp = (float*)(wsb + off);                  off += ND * 4;        // fp32
    float* q2g  = (float*)(wsb + off);                  off += (size_t)B_ * H_ * S_ * 4;
    float* k2g  = (float*)(wsb + off);                  off += (size_t)B_ * H_ * S_ * 4;
    unsigned short* h2b = (unsigned short*)(wsb + off); off += ND * 2;        // SLN2 out
    // ---- dead pool (all dead before the MLP) ----
    size_t pool0 = off;
    unsigned short* Wqkvt = (unsigned short*)(wsb + off); off += 3538944;     // [2304][768]
    unsigned short* Wot   = (unsigned short*)(wsb + off); off += 1179648;     // [768][768]
    unsigned short* h1b   = (unsigned short*)(wsb + off); off += ND * 2;      // alias: attnb
    unsigned short* vtg   = (unsigned short*)(wsb + off); off += (size_t)1024 * 14336;
    unsigned short* qkvb  = (unsigned short*)(wsb + off); off += (size_t)NTOK * QKVW * 2;
    unsigned short* attnb   = h1b;
    unsigned short* hiddenb = (unsigned short*)(wsb + pool0);  // [8192][3072] bf16 overlay

    // --- weight prep (transpose + bf16) ---
    dim3 tb(32, 8);
    transpose_bf16_kernel<<<dim3(768/32, 768/32), tb, 0, stream>>>(Wq, Wqkvt,              768, 768);
    transpose_bf16_kernel<<<dim3(768/32, 768/32), tb, 0, stream>>>(Wk, Wqkvt + 768*768,    768, 768);
    transpose_bf16_kernel<<<dim3(768/32, 768/32), tb, 0, stream>>>(Wv, Wqkvt + 2*768*768,  768, 768);
    transpose_bf16_kernel<<<dim3(768/32, 768/32), tb, 0, stream>>>(Wo, Wot, 768, 768);
    transpose_bf16_kernel<<<dim3(3072/32, 768/32), tb, 0, stream>>>(W1, W1t, 768, 3072);
    transpose_bf16_kernel<<<dim3(768/32, 3072/32), tb, 0, stream>>>(W2, W2t, 3072, 768);
    concat_bias_kernel<<<9, 256, 0, stream>>>(bq, bk, bv, bqkv);

    // 1. SLN1 -> h1b (bf16), copy x -> out[0:ND]
    sln_kernel<<<NTOK, 192, 0, stream>>>(h, x, g1, be1, ln1w, ln1b, h1b, out);

    // 2. fused QKV GEMM: [8192,768] @ [768,2304] -> qkvb bf16
    gemm_mfma_kernel<1, 0><<<dim3(NTOK/128, QKVW/128), 256, 0, stream>>>(
        h1b, Wqkvt, bqkv, nullptr, qkvb, NTOK, QKVW, D_);

    // 3. norms + V transpose tiles
    norms_kernel<<<NTOK, 256, 0, stream>>>(qkvb, q2g, k2g);
    vtrans_kernel<<<1024, 256, 0, stream>>>(qkvb, vtg);

    // 4. MFMA attention -> attnb bf16
    attn_mfma_kernel<<<512, 256, 0, stream>>>(qkvb, vtg, q2g, k2g, attnb);

    // 5. Wo projection + residual h -> htmp fp32
    gemm_mfma_kernel<0, 0><<<dim3(NTOK/128, D_/128), 256, 0, stream>>>(
        attnb, Wot, bo, h, htmp, NTOK, D_, D_);

    // 6. SLN2 -> h2b bf16
    sln_kernel<<<NTOK, 192, 0, stream>>>(htmp, x, g2, be2, ln2w, ln2b, h2b, nullptr);

    // 7. MLP, full-size single dispatches (hidden overlays dead pool)
    gemm_mfma_kernel<1, 1><<<dim3(NTOK/128, DFF_/128), 256, 0, stream>>>(
        h2b, W1t, b1, nullptr, hiddenb, NTOK, DFF_, D_);
    gemm_mfma_kernel<0, 0><<<dim3(NTOK/128, D_/128), 256, 0, stream>>>(
        hiddenb, W2t, b2, htmp, out + ND, NTOK, D_, DFF_);

    (void)in_sizes; (void)n_in; (void)out_size; (void)ws_size;
}

// Round 5
// 468.708 us; speedup vs baseline: 6.7632x; 1.0696x over previous
//
#include <hip/hip_runtime.h>
#include <math.h>

#define B_ 8
#define S_ 1024
#define D_ 768
#define H_ 8
#define DH_ 96
#define DFF_ 3072
#define NTOK (B_*S_)
#define QKVW 2304            // fused q|k|v width
#define EPS_ 1e-5f

typedef __attribute__((ext_vector_type(4))) float f4;
typedef __attribute__((ext_vector_type(4))) int i4;
typedef __attribute__((ext_vector_type(8))) __bf16 bf16x8;
typedef __attribute__((ext_vector_type(4))) unsigned short us4;
typedef __attribute__((ext_vector_type(8))) unsigned short us8;

static __device__ __forceinline__ unsigned short f2bf(float f) {
    unsigned int u = __builtin_bit_cast(unsigned int, f);
    u += 0x7fffu + ((u >> 16) & 1u);
    return (unsigned short)(u >> 16);
}
static __device__ __forceinline__ float bf2f(unsigned short u) {
    unsigned int x = ((unsigned int)u) << 16;
    return __builtin_bit_cast(float, x);
}

#define GLOBAL_LOAD_LDS16(g, l) \
    __builtin_amdgcn_global_load_lds((const __attribute__((address_space(1))) unsigned int*)(g), \
                                     (__attribute__((address_space(3))) unsigned int*)(l), 16, 0, 0)

// ---------------------------------------------------------------------------
// SLN: out_bf16 = bf16( x * (gamma * LayerNorm(h) + beta) ); optional x copy (fp32)
// ---------------------------------------------------------------------------
__global__ __launch_bounds__(192) void sln_kernel(
    const float* __restrict__ h, const float* __restrict__ x,
    const float* __restrict__ gamma, const float* __restrict__ beta,
    const float* __restrict__ w, const float* __restrict__ bvec,
    unsigned short* __restrict__ out_bf, float* __restrict__ xcopy)
{
    int row = blockIdx.x;
    int t = threadIdx.x;
    const float4* h4 = (const float4*)(h + (size_t)row * D_);
    const float4* x4 = (const float4*)(x + (size_t)row * D_);
    float4 hv = h4[t];
    float s  = hv.x + hv.y + hv.z + hv.w;
    float ss = hv.x*hv.x + hv.y*hv.y + hv.z*hv.z + hv.w*hv.w;
    #pragma unroll
    for (int off = 32; off > 0; off >>= 1) {
        s  += __shfl_down(s, off);
        ss += __shfl_down(ss, off);
    }
    __shared__ float red[2][3];
    int wid = t >> 6;
    if ((t & 63) == 0) { red[0][wid] = s; red[1][wid] = ss; }
    __syncthreads();
    float sum   = red[0][0] + red[0][1] + red[0][2];
    float sumsq = red[1][0] + red[1][1] + red[1][2];
    float mu  = sum * (1.0f / D_);
    float var = sumsq * (1.0f / D_) - mu * mu;
    float rstd = rsqrtf(var + EPS_);
    float g = gamma[0], be = beta[0];
    float4 wv = ((const float4*)w)[t];
    float4 bv = ((const float4*)bvec)[t];
    float4 xv = x4[t];
    us4 o;
    o.x = f2bf(xv.x * (g * ((hv.x - mu) * rstd * wv.x + bv.x) + be));
    o.y = f2bf(xv.y * (g * ((hv.y - mu) * rstd * wv.y + bv.y) + be));
    o.z = f2bf(xv.z * (g * ((hv.z - mu) * rstd * wv.z + bv.z) + be));
    o.w = f2bf(xv.w * (g * ((hv.w - mu) * rstd * wv.w + bv.w) + be));
    *(us4*)(out_bf + (size_t)row * D_ + t * 4) = o;
    if (xcopy) ((float4*)(xcopy + (size_t)row * D_))[t] = xv;
}

// ---------------------------------------------------------------------------
// Tiled transpose + fp32->bf16: in [K][N] fp32 -> out [N][K] bf16
// ---------------------------------------------------------------------------
__global__ __launch_bounds__(256) void transpose_bf16_kernel(
    const float* __restrict__ in, unsigned short* __restrict__ out, int K, int N)
{
    __shared__ float tile[32][33];
    int n0 = blockIdx.x * 32, k0 = blockIdx.y * 32;
    int tx = threadIdx.x, ty = threadIdx.y;   // 32 x 8
    #pragma unroll
    for (int r = 0; r < 4; r++)
        tile[ty + r * 8][tx] = in[(size_t)(k0 + ty + r * 8) * N + n0 + tx];
    __syncthreads();
    #pragma unroll
    for (int r = 0; r < 4; r++)
        out[(size_t)(n0 + ty + r * 8) * K + k0 + tx] = f2bf(tile[tx][ty + r * 8]);
}

__global__ void concat_bias_kernel(const float* __restrict__ bq, const float* __restrict__ bk,
                                   const float* __restrict__ bv, float* __restrict__ outb)
{
    int i = blockIdx.x * 256 + threadIdx.x;
    if (i >= QKVW) return;
    float v = (i < 768) ? bq[i] : (i < 1536) ? bk[i - 768] : bv[i - 1536];
    outb[i] = v;
}

// ---------------------------------------------------------------------------
// bf16 MFMA GEMM, 128x128 tile, operand-swapped vectorized epilogue.
// ---------------------------------------------------------------------------
template<int OUT_BF16, int RELU>
__global__ __launch_bounds__(256) void gemm_mfma_kernel(
    const unsigned short* __restrict__ A, const unsigned short* __restrict__ Bt,
    const float* __restrict__ bias, const float* __restrict__ resid,
    void* __restrict__ Cout, int M, int N, int K)
{
    __shared__ unsigned short Asm[128 * 32];
    __shared__ unsigned short Bsm[128 * 32];

    int t = threadIdx.x;
    int lane = t & 63, wv = t >> 6;
    int wm = wv & 1, wn = wv >> 1;
    int l16 = lane & 15, quad = lane >> 4;

    int bm = blockIdx.x * 128;
    int bn = blockIdx.y * 128;

    const unsigned short* Abase = A  + (size_t)bm * K;
    const unsigned short* Bbase = Bt + (size_t)bn * K;

    int fl0 = t, fl1 = 256 + t;
    int r0s = fl0 >> 2, kc0 = (fl0 & 3) << 3;
    int r1s = fl1 >> 2, kc1 = (fl1 & 3) << 3;

    f4 acc[4][4] = {};   // acc[j][i]: j = weight (col) tile, i = act (row) tile

    for (int k0 = 0; k0 < K; k0 += 32) {
        __syncthreads();
        GLOBAL_LOAD_LDS16(Abase + (size_t)r0s * K + k0 + kc0, &Asm[fl0 * 8]);
        GLOBAL_LOAD_LDS16(Abase + (size_t)r1s * K + k0 + kc1, &Asm[fl1 * 8]);
        GLOBAL_LOAD_LDS16(Bbase + (size_t)r0s * K + k0 + kc0, &Bsm[fl0 * 8]);
        GLOBAL_LOAD_LDS16(Bbase + (size_t)r1s * K + k0 + kc1, &Bsm[fl1 * 8]);
        __syncthreads();

        bf16x8 xf[4], wf[4];
        #pragma unroll
        for (int i = 0; i < 4; i++) {
            int m = wm * 64 + i * 16 + l16;
            xf[i] = __builtin_bit_cast(bf16x8, *(const i4*)&Asm[m * 32 + quad * 8]);
        }
        #pragma unroll
        for (int j = 0; j < 4; j++) {
            int n = wn * 64 + j * 16 + l16;
            wf[j] = __builtin_bit_cast(bf16x8, *(const i4*)&Bsm[n * 32 + quad * 8]);
        }
        #pragma unroll
        for (int j = 0; j < 4; j++)
            #pragma unroll
            for (int i = 0; i < 4; i++)
                acc[j][i] = __builtin_amdgcn_mfma_f32_16x16x32_bf16(wf[j], xf[i], acc[j][i], 0, 0, 0);
    }

    #pragma unroll
    for (int i = 0; i < 4; i++) {
        int rowg = bm + wm * 64 + i * 16 + l16;
        #pragma unroll
        for (int j = 0; j < 4; j++) {
            int colg0 = bn + wn * 64 + j * 16 + quad * 4;
            f4 v = acc[j][i];
            f4 b4 = *(const f4*)&bias[colg0];
            v += b4;
            if (RELU) {
                #pragma unroll
                for (int r = 0; r < 4; r++) v[r] = fmaxf(v[r], 0.f);
            }
            if (resid) {
                f4 r4 = *(const f4*)&resid[(size_t)rowg * N + colg0];
                v += r4;
            }
            if (OUT_BF16) {
                us4 o;
                o.x = f2bf(v[0]); o.y = f2bf(v[1]); o.z = f2bf(v[2]); o.w = f2bf(v[3]);
                *(us4*)((unsigned short*)Cout + (size_t)rowg * N + colg0) = o;
            } else {
                *(f4*)((float*)Cout + (size_t)rowg * N + colg0) = v;
            }
        }
    }
}

// ---------------------------------------------------------------------------
// bf16 MFMA GEMM, 128x64 tile (for N=768 GEMMs: 3 blocks/CU instead of 1.5).
// ---------------------------------------------------------------------------
template<int OUT_BF16, int RELU>
__global__ __launch_bounds__(256) void gemm_mfma_n64_kernel(
    const unsigned short* __restrict__ A, const unsigned short* __restrict__ Bt,
    const float* __restrict__ bias, const float* __restrict__ resid,
    void* __restrict__ Cout, int M, int N, int K)
{
    __shared__ unsigned short Asm[128 * 32];
    __shared__ unsigned short Bsm[64 * 32];

    int t = threadIdx.x;
    int lane = t & 63, wv = t >> 6;
    int wm = wv & 1, wn = wv >> 1;
    int l16 = lane & 15, quad = lane >> 4;

    int bm = blockIdx.x * 128;
    int bn = blockIdx.y * 64;

    const unsigned short* Abase = A  + (size_t)bm * K;
    const unsigned short* Bbase = Bt + (size_t)bn * K;

    int fl0 = t, fl1 = 256 + t;
    int r0s = fl0 >> 2, kc0 = (fl0 & 3) << 3;
    int r1s = fl1 >> 2, kc1 = (fl1 & 3) << 3;

    f4 acc[2][4] = {};

    for (int k0 = 0; k0 < K; k0 += 32) {
        __syncthreads();
        GLOBAL_LOAD_LDS16(Abase + (size_t)r0s * K + k0 + kc0, &Asm[fl0 * 8]);
        GLOBAL_LOAD_LDS16(Abase + (size_t)r1s * K + k0 + kc1, &Asm[fl1 * 8]);
        GLOBAL_LOAD_LDS16(Bbase + (size_t)r0s * K + k0 + kc0, &Bsm[fl0 * 8]);
        __syncthreads();

        bf16x8 xf[4], wf[2];
        #pragma unroll
        for (int i = 0; i < 4; i++) {
            int m = wm * 64 + i * 16 + l16;
            xf[i] = __builtin_bit_cast(bf16x8, *(const i4*)&Asm[m * 32 + quad * 8]);
        }
        #pragma unroll
        for (int j = 0; j < 2; j++) {
            int n = wn * 32 + j * 16 + l16;
            wf[j] = __builtin_bit_cast(bf16x8, *(const i4*)&Bsm[n * 32 + quad * 8]);
        }
        #pragma unroll
        for (int j = 0; j < 2; j++)
            #pragma unroll
            for (int i = 0; i < 4; i++)
                acc[j][i] = __builtin_amdgcn_mfma_f32_16x16x32_bf16(wf[j], xf[i], acc[j][i], 0, 0, 0);
    }

    #pragma unroll
    for (int i = 0; i < 4; i++) {
        int rowg = bm + wm * 64 + i * 16 + l16;
        #pragma unroll
        for (int j = 0; j < 2; j++) {
            int colg0 = bn + wn * 32 + j * 16 + quad * 4;
            f4 v = acc[j][i];
            f4 b4 = *(const f4*)&bias[colg0];
            v += b4;
            if (RELU) {
                #pragma unroll
                for (int r = 0; r < 4; r++) v[r] = fmaxf(v[r], 0.f);
            }
            if (resid) {
                f4 r4 = *(const f4*)&resid[(size_t)rowg * N + colg0];
                v += r4;
            }
            if (OUT_BF16) {
                us4 o;
                o.x = f2bf(v[0]); o.y = f2bf(v[1]); o.z = f2bf(v[2]); o.w = f2bf(v[3]);
                *(us4*)((unsigned short*)Cout + (size_t)rowg * N + colg0) = o;
            } else {
                *(f4*)((float*)Cout + (size_t)rowg * N + colg0) = v;
            }
        }
    }
}

// ---------------------------------------------------------------------------
// q2/k2 norms from fused qkv bf16 buffer [NTOK][2304] -> q2g,k2g [B*H*S] fp32
// ---------------------------------------------------------------------------
__global__ __launch_bounds__(256) void norms_kernel(
    const unsigned short* __restrict__ qkv, float* __restrict__ q2g, float* __restrict__ k2g)
{
    int row = blockIdx.x;
    int t = threadIdx.x;
    int hh = t >> 5, l32 = t & 31;
    const unsigned short* base = qkv + (size_t)row * QKVW + hh * DH_ + l32 * 3;
    float qs = 0.f, ks = 0.f;
    #pragma unroll
    for (int e = 0; e < 3; e++) {
        float qv = bf2f(base[e]);
        float kv = bf2f(base[768 + e]);
        qs += qv * qv; ks += kv * kv;
    }
    #pragma unroll
    for (int off = 16; off > 0; off >>= 1) {
        qs += __shfl_xor(qs, off, 32);
        ks += __shfl_xor(ks, off, 32);
    }
    if (l32 == 0) {
        int b = row >> 10, s = row & 1023;
        int idx = (b * H_ + hh) * S_ + s;
        q2g[idx] = qs; k2g[idx] = ks;
    }
}

// ---------------------------------------------------------------------------
// V transpose into padded tiles: qkv V-part -> vt[(bh*16+kt)] tile of [96][72] bf16
// ---------------------------------------------------------------------------
__global__ __launch_bounds__(256) void vtrans_kernel(
    const unsigned short* __restrict__ qkv, unsigned short* __restrict__ vt)
{
    __shared__ unsigned short Vl[64][100];
    int blk = blockIdx.x;          // bh*16 + kt
    int bh = blk >> 4, kt = blk & 15;
    int b = bh >> 3, hh = bh & 7;
    int t = threadIdx.x;
    int key = t >> 2, qc = t & 3;
    const unsigned short* src = qkv + ((size_t)(b * S_ + kt * 64 + key)) * QKVW + 1536 + hh * DH_;
    #pragma unroll
    for (int i = 0; i < 3; i++) {
        int chunk = qc + i * 4;            // 0..11, 8 shorts each
        us8 v = *(const us8*)(src + chunk * 8);
        #pragma unroll
        for (int e = 0; e < 8; e++) Vl[key][chunk * 8 + e] = v[e];
    }
    __syncthreads();
    unsigned short* dst = vt + (size_t)blk * 7168;
    #pragma unroll
    for (int r = 0; r < 3; r++) {
        int c = r * 256 + t;               // 0..767
        int vd = c >> 3, kc = c & 7;
        us8 o;
        #pragma unroll
        for (int j = 0; j < 8; j++) o[j] = Vl[kc * 8 + j][vd];
        *(us8*)(dst + vd * 72 + kc * 8) = o;
    }
}

// ---------------------------------------------------------------------------
// MFMA flash attention with L2 distances.
// grid = 64 heads * 16 qtiles = 1024 blocks; 4 waves; wave = 16 q-rows; TK=64.
// Softmax tracked in exp2 domain (log2e/sqrt(DH) folded into one constant).
// LDS 35.8KB -> 4 blocks/CU.
// ---------------------------------------------------------------------------
__global__ __launch_bounds__(256, 4) void attn_mfma_kernel(
    const unsigned short* __restrict__ qkv,
    const unsigned short* __restrict__ vt,
    const float* __restrict__ q2g, const float* __restrict__ k2g,
    unsigned short* __restrict__ outb)
{
    __shared__ unsigned short Klds[64 * 96];     // [key][d]
    __shared__ unsigned short Vlds[7168];        // [vdim][72]
    __shared__ unsigned short Plds[4][16 * 72];  // per-wave [qrow][key], stride 72

    int t = threadIdx.x;
    int lane = t & 63, w = t >> 6;
    int l16 = lane & 15, quad = lane >> 4;

    int bh = blockIdx.x >> 4;
    int qt = blockIdx.x & 15;
    int b = bh >> 3, hh = bh & 7;

    int qrow0 = qt * 64 + w * 16;

    const unsigned short* qb = qkv + ((size_t)(b * S_ + qrow0)) * QKVW + hh * DH_;
    bf16x8 qf[3];
    #pragma unroll
    for (int d = 0; d < 3; d++)
        qf[d] = __builtin_bit_cast(bf16x8,
            *(const i4*)(qb + (size_t)l16 * QKVW + d * 32 + quad * 8));

    float q2n = q2g[bh * S_ + qrow0 + l16];

    float mrun = -INFINITY;   // exp2-domain max
    float lrun = 0.f;
    f4 Oacc[6] = {};

    const float cexp = 0.14724445f;   // log2(e)/sqrt(96)

    const unsigned short* kgb = qkv + ((size_t)(b * S_)) * QKVW + 768 + hh * DH_;
    const unsigned short* vgb0 = vt + (size_t)(bh * 16) * 7168;

    for (int it = 0; it < 16; it++) {
        __syncthreads();
        #pragma unroll
        for (int r = 0; r < 3; r++) {
            int c = r * 256 + t;
            int key = c / 12, dc = c % 12;
            GLOBAL_LOAD_LDS16(kgb + ((size_t)(it * 64 + key)) * QKVW + dc * 8, &Klds[c * 8]);
        }
        const unsigned short* vgb = vgb0 + (size_t)it * 7168;
        #pragma unroll
        for (int r = 0; r < 3; r++)
            GLOBAL_LOAD_LDS16(vgb + (r * 256 + t) * 8, &Vlds[(r * 256 + t) * 8]);
        if (t < 128)
            GLOBAL_LOAD_LDS16(vgb + (768 + t) * 8, &Vlds[(768 + t) * 8]);
        __syncthreads();

        // S^T = K . Q^T : C-frag col(l16)=qrow, row(quad*4+r)=key
        f4 sf[4];
        #pragma unroll
        for (int kt2 = 0; kt2 < 4; kt2++) {
            bf16x8 kf0 = __builtin_bit_cast(bf16x8, *(const i4*)&Klds[(kt2 * 16 + l16) * 96 + quad * 8]);
            bf16x8 kf1 = __builtin_bit_cast(bf16x8, *(const i4*)&Klds[(kt2 * 16 + l16) * 96 + 32 + quad * 8]);
            bf16x8 kf2 = __builtin_bit_cast(bf16x8, *(const i4*)&Klds[(kt2 * 16 + l16) * 96 + 64 + quad * 8]);
            f4 a = {};
            a = __builtin_amdgcn_mfma_f32_16x16x32_bf16(kf0, qf[0], a, 0, 0, 0);
            a = __builtin_amdgcn_mfma_f32_16x16x32_bf16(kf1, qf[1], a, 0, 0, 0);
            a = __builtin_amdgcn_mfma_f32_16x16x32_bf16(kf2, qf[2], a, 0, 0, 0);
            sf[kt2] = a;
        }
        // scores in exp2 domain: s' = -sqrt(max(q2+k2-2qk,0)) * log2e/sqrt(DH)
        #pragma unroll
        for (int kt2 = 0; kt2 < 4; kt2++) {
            float4 k2f = *(const float4*)(k2g + bh * S_ + it * 64 + kt2 * 16 + quad * 4);
            float k2a[4] = {k2f.x, k2f.y, k2f.z, k2f.w};
            f4 s = sf[kt2];
            #pragma unroll
            for (int r2 = 0; r2 < 4; r2++) {
                float d2 = fmaxf(q2n + k2a[r2] - 2.f * s[r2], 0.f);
                s[r2] = -__builtin_amdgcn_sqrtf(d2) * cexp;
            }
            sf[kt2] = s;
        }
        // online softmax (exp2 domain)
        f4 m4 = sf[0];
        #pragma unroll
        for (int kt2 = 1; kt2 < 4; kt2++)
            #pragma unroll
            for (int r2 = 0; r2 < 4; r2++)
                m4[r2] = fmaxf(m4[r2], sf[kt2][r2]);
        float mx = fmaxf(fmaxf(m4[0], m4[1]), fmaxf(m4[2], m4[3]));
        mx = fmaxf(mx, __shfl_xor(mx, 16, 64));
        mx = fmaxf(mx, __shfl_xor(mx, 32, 64));
        float mnew = fmaxf(mrun, mx);
        float alph = exp2f(mrun - mnew);
        mrun = mnew;
        float ssum = 0.f;
        #pragma unroll
        for (int kt2 = 0; kt2 < 4; kt2++) {
            f4 s = sf[kt2];
            #pragma unroll
            for (int r2 = 0; r2 < 4; r2++) { s[r2] = exp2f(s[r2] - mnew); ssum += s[r2]; }
            sf[kt2] = s;
        }
        ssum += __shfl_xor(ssum, 16, 64);
        ssum += __shfl_xor(ssum, 32, 64);
        lrun = lrun * alph + ssum;
        // pack P (bf16) into per-wave LDS [qrow=l16][key]
        #pragma unroll
        for (int kt2 = 0; kt2 < 4; kt2++) {
            f4 s = sf[kt2];
            uint2 pk;
            pk.x = (unsigned)f2bf(s[0]) | ((unsigned)f2bf(s[1]) << 16);
            pk.y = (unsigned)f2bf(s[2]) | ((unsigned)f2bf(s[3]) << 16);
            *(uint2*)&Plds[w][l16 * 72 + kt2 * 16 + quad * 4] = pk;
        }
        // rescale O by alpha (broadcast to C-layout rows: qrow = quad*4+r2)
        f4 av;
        #pragma unroll
        for (int r2 = 0; r2 < 4; r2++)
            av[r2] = __shfl(alph, quad * 4 + r2, 64);
        #pragma unroll
        for (int vtl = 0; vtl < 6; vtl++)
            #pragma unroll
            for (int r2 = 0; r2 < 4; r2++)
                Oacc[vtl][r2] *= av[r2];
        // O += P . V
        bf16x8 pa0 = __builtin_bit_cast(bf16x8, *(const i4*)&Plds[w][l16 * 72 + quad * 8]);
        bf16x8 pa1 = __builtin_bit_cast(bf16x8, *(const i4*)&Plds[w][l16 * 72 + 32 + quad * 8]);
        #pragma unroll
        for (int vtl = 0; vtl < 6; vtl++) {
            bf16x8 vf0 = __builtin_bit_cast(bf16x8, *(const i4*)&Vlds[(vtl * 16 + l16) * 72 + quad * 8]);
            bf16x8 vf1 = __builtin_bit_cast(bf16x8, *(const i4*)&Vlds[(vtl * 16 + l16) * 72 + 32 + quad * 8]);
            Oacc[vtl] = __builtin_amdgcn_mfma_f32_16x16x32_bf16(pa0, vf0, Oacc[vtl], 0, 0, 0);
            Oacc[vtl] = __builtin_amdgcn_mfma_f32_16x16x32_bf16(pa1, vf1, Oacc[vtl], 0, 0, 0);
        }
    }
    float inv_l = 1.f / lrun;
    f4 iv;
    #pragma unroll
    for (int r2 = 0; r2 < 4; r2++)
        iv[r2] = __shfl(inv_l, quad * 4 + r2, 64);
    #pragma unroll
    for (int vtl = 0; vtl < 6; vtl++)
        #pragma unroll
        for (int r2 = 0; r2 < 4; r2++) {
            int row = b * S_ + qrow0 + quad * 4 + r2;
            outb[(size_t)row * D_ + hh * DH_ + vtl * 16 + l16] = f2bf(Oacc[vtl][r2] * iv[r2]);
        }
}

// ---------------------------------------------------------------------------
extern "C" void kernel_launch(void* const* d_in, const int* in_sizes, int n_in,
                              void* d_out, int out_size, void* d_ws, size_t ws_size,
                              hipStream_t stream)
{
    const float* h    = (const float*)d_in[0];
    const float* x    = (const float*)d_in[1];
    const float* g1   = (const float*)d_in[2];
    const float* be1  = (const float*)d_in[3];
    const float* ln1w = (const float*)d_in[4];
    const float* ln1b = (const float*)d_in[5];
    const float* g2   = (const float*)d_in[6];
    const float* be2  = (const float*)d_in[7];
    const float* ln2w = (const float*)d_in[8];
    const float* ln2b = (const float*)d_in[9];
    const float* Wq   = (const float*)d_in[10];
    const float* bq   = (const float*)d_in[11];
    const float* Wk   = (const float*)d_in[12];
    const float* bk   = (const float*)d_in[13];
    const float* Wv   = (const float*)d_in[14];
    const float* bv   = (const float*)d_in[15];
    const float* Wo   = (const float*)d_in[16];
    const float* bo   = (const float*)d_in[17];
    const float* W1   = (const float*)d_in[18];
    const float* b1   = (const float*)d_in[19];
    const float* W2   = (const float*)d_in[20];
    const float* b2   = (const float*)d_in[21];

    float* out = (float*)d_out;
    char* wsb = (char*)d_ws;
    const size_t ND = (size_t)NTOK * D_;

    // workspace layout (bytes): persistent region first, dead-pool last so
    // the full-size MLP hidden (50.3 MB bf16) can overlay the dead pool.
    size_t off = 0;
    unsigned short* W1t = (unsigned short*)(wsb + off); off += 4718592;       // [3072][768]
    unsigned short* W2t = (unsigned short*)(wsb + off); off += 4718592;       // [768][3072]
    float* bqkv = (float*)(wsb + off);                  off += 16384;
    float* htmp = (float*)(wsb + off);                  off += ND * 4;        // fp32
    float* q2g  = (float*)(wsb + off);                  off += (size_t)B_ * H_ * S_ * 4;
    float* k2g  = (float*)(wsb + off);                  off += (size_t)B_ * H_ * S_ * 4;
    unsigned short* h2b = (unsigned short*)(wsb + off); off += ND * 2;        // SLN2 out
    // ---- dead pool (all dead before the MLP) ----
    size_t pool0 = off;
    unsigned short* Wqkvt = (unsigned short*)(wsb + off); off += 3538944;     // [2304][768]
    unsigned short* Wot   = (unsigned short*)(wsb + off); off += 1179648;     // [768][768]
    unsigned short* h1b   = (unsigned short*)(wsb + off); off += ND * 2;      // alias: attnb
    unsigned short* vtg   = (unsigned short*)(wsb + off); off += (size_t)1024 * 14336;
    unsigned short* qkvb  = (unsigned short*)(wsb + off); off += (size_t)NTOK * QKVW * 2;
    unsigned short* attnb   = h1b;
    unsigned short* hiddenb = (unsigned short*)(wsb + pool0);  // [8192][3072] bf16 overlay

    // --- weight prep (transpose + bf16) ---
    dim3 tb(32, 8);
    transpose_bf16_kernel<<<dim3(768/32, 768/32), tb, 0, stream>>>(Wq, Wqkvt,              768, 768);
    transpose_bf16_kernel<<<dim3(768/32, 768/32), tb, 0, stream>>>(Wk, Wqkvt + 768*768,    768, 768);
    transpose_bf16_kernel<<<dim3(768/32, 768/32), tb, 0, stream>>>(Wv, Wqkvt + 2*768*768,  768, 768);
    transpose_bf16_kernel<<<dim3(768/32, 768/32), tb, 0, stream>>>(Wo, Wot, 768, 768);
    transpose_bf16_kernel<<<dim3(3072/32, 768/32), tb, 0, stream>>>(W1, W1t, 768, 3072);
    transpose_bf16_kernel<<<dim3(768/32, 3072/32), tb, 0, stream>>>(W2, W2t, 3072, 768);
    concat_bias_kernel<<<9, 256, 0, stream>>>(bq, bk, bv, bqkv);

    // 1. SLN1 -> h1b (bf16), copy x -> out[0:ND]
    sln_kernel<<<NTOK, 192, 0, stream>>>(h, x, g1, be1, ln1w, ln1b, h1b, out);

    // 2. fused QKV GEMM: [8192,768] @ [768,2304] -> qkvb bf16
    gemm_mfma_kernel<1, 0><<<dim3(NTOK/128, QKVW/128), 256, 0, stream>>>(
        h1b, Wqkvt, bqkv, nullptr, qkvb, NTOK, QKVW, D_);

    // 3. norms + V transpose tiles
    norms_kernel<<<NTOK, 256, 0, stream>>>(qkvb, q2g, k2g);
    vtrans_kernel<<<1024, 256, 0, stream>>>(qkvb, vtg);

    // 4. MFMA attention -> attnb bf16
    attn_mfma_kernel<<<1024, 256, 0, stream>>>(qkvb, vtg, q2g, k2g, attnb);

    // 5. Wo projection + residual h -> htmp fp32 (128x64 tiles: 768 blocks)
    gemm_mfma_n64_kernel<0, 0><<<dim3(NTOK/128, D_/64), 256, 0, stream>>>(
        attnb, Wot, bo, h, htmp, NTOK, D_, D_);

    // 6. SLN2 -> h2b bf16
    sln_kernel<<<NTOK, 192, 0, stream>>>(htmp, x, g2, be2, ln2w, ln2b, h2b, nullptr);

    // 7. MLP, full-size single dispatches
    gemm_mfma_kernel<1, 1><<<dim3(NTOK/128, DFF_/128), 256, 0, stream>>>(
        h2b, W1t, b1, nullptr, hiddenb, NTOK, DFF_, D_);
    gemm_mfma_n64_kernel<0, 0><<<dim3(NTOK/128, D_/64), 256, 0, stream>>>(
        hiddenb, W2t, b2, htmp, out + ND, NTOK, D_, DFF_);

    (void)in_sizes; (void)n_in; (void)out_size; (void)ws_size;
}

// Round 6
// 453.527 us; speedup vs baseline: 6.9896x; 1.0335x over previous
//
#include <hip/hip_runtime.h>
#include <math.h>

#define B_ 8
#define S_ 1024
#define D_ 768
#define H_ 8
#define DH_ 96
#define DFF_ 3072
#define NTOK (B_*S_)
#define QKVW 2304            // fused q|k|v width
#define EPS_ 1e-5f

typedef __attribute__((ext_vector_type(4))) float f4;
typedef __attribute__((ext_vector_type(4))) int i4;
typedef __attribute__((ext_vector_type(8))) __bf16 bf16x8;
typedef __attribute__((ext_vector_type(4))) unsigned short us4;
typedef __attribute__((ext_vector_type(8))) unsigned short us8;

static __device__ __forceinline__ unsigned short f2bf(float f) {
    unsigned int u = __builtin_bit_cast(unsigned int, f);
    u += 0x7fffu + ((u >> 16) & 1u);
    return (unsigned short)(u >> 16);
}
static __device__ __forceinline__ float bf2f(unsigned short u) {
    unsigned int x = ((unsigned int)u) << 16;
    return __builtin_bit_cast(float, x);
}

#define GLOBAL_LOAD_LDS16(g, l) \
    __builtin_amdgcn_global_load_lds((const __attribute__((address_space(1))) unsigned int*)(g), \
                                     (__attribute__((address_space(3))) unsigned int*)(l), 16, 0, 0)

// ---------------------------------------------------------------------------
// SLN: out_bf16 = bf16( x * (gamma * LayerNorm(h) + beta) ); optional x copy (fp32)
// ---------------------------------------------------------------------------
__global__ __launch_bounds__(192) void sln_kernel(
    const float* __restrict__ h, const float* __restrict__ x,
    const float* __restrict__ gamma, const float* __restrict__ beta,
    const float* __restrict__ w, const float* __restrict__ bvec,
    unsigned short* __restrict__ out_bf, float* __restrict__ xcopy)
{
    int row = blockIdx.x;
    int t = threadIdx.x;
    const float4* h4 = (const float4*)(h + (size_t)row * D_);
    const float4* x4 = (const float4*)(x + (size_t)row * D_);
    float4 hv = h4[t];
    float s  = hv.x + hv.y + hv.z + hv.w;
    float ss = hv.x*hv.x + hv.y*hv.y + hv.z*hv.z + hv.w*hv.w;
    #pragma unroll
    for (int off = 32; off > 0; off >>= 1) {
        s  += __shfl_down(s, off);
        ss += __shfl_down(ss, off);
    }
    __shared__ float red[2][3];
    int wid = t >> 6;
    if ((t & 63) == 0) { red[0][wid] = s; red[1][wid] = ss; }
    __syncthreads();
    float sum   = red[0][0] + red[0][1] + red[0][2];
    float sumsq = red[1][0] + red[1][1] + red[1][2];
    float mu  = sum * (1.0f / D_);
    float var = sumsq * (1.0f / D_) - mu * mu;
    float rstd = rsqrtf(var + EPS_);
    float g = gamma[0], be = beta[0];
    float4 wv = ((const float4*)w)[t];
    float4 bv = ((const float4*)bvec)[t];
    float4 xv = x4[t];
    us4 o;
    o.x = f2bf(xv.x * (g * ((hv.x - mu) * rstd * wv.x + bv.x) + be));
    o.y = f2bf(xv.y * (g * ((hv.y - mu) * rstd * wv.y + bv.y) + be));
    o.z = f2bf(xv.z * (g * ((hv.z - mu) * rstd * wv.z + bv.z) + be));
    o.w = f2bf(xv.w * (g * ((hv.w - mu) * rstd * wv.w + bv.w) + be));
    *(us4*)(out_bf + (size_t)row * D_ + t * 4) = o;
    if (xcopy) ((float4*)(xcopy + (size_t)row * D_))[t] = xv;
}

// ---------------------------------------------------------------------------
// Merged weight prep: all 6 transposes (fp32->bf16, [K][N]->[N][K]) + bias concat
// block dim (32,8). grid = 6912 transpose tiles + 9 bias blocks.
// ---------------------------------------------------------------------------
__global__ __launch_bounds__(256) void prep_all_kernel(
    const float* __restrict__ Wq, const float* __restrict__ Wk,
    const float* __restrict__ Wv, const float* __restrict__ Wo,
    const float* __restrict__ W1, const float* __restrict__ W2,
    const float* __restrict__ bq, const float* __restrict__ bk, const float* __restrict__ bv,
    unsigned short* __restrict__ Wqkvt, unsigned short* __restrict__ Wot,
    unsigned short* __restrict__ W1t, unsigned short* __restrict__ W2t,
    float* __restrict__ bqkv)
{
    int id = blockIdx.x;
    int tx = threadIdx.x, ty = threadIdx.y;
    if (id >= 6912) {   // bias concat: 9 blocks x 256 threads
        int i = (id - 6912) * 256 + ty * 32 + tx;
        if (i < QKVW) {
            float v = (i < 768) ? bq[i] : (i < 1536) ? bk[i - 768] : bv[i - 1536];
            bqkv[i] = v;
        }
        return;
    }
    const float* in; unsigned short* out; int K, N, nbx, rel;
    if (id < 1728)      { int m = id / 576; rel = id % 576;
                          in = (m == 0) ? Wq : (m == 1) ? Wk : Wv;
                          out = Wqkvt + (size_t)m * 768 * 768; K = 768; N = 768; nbx = 24; }
    else if (id < 2304) { rel = id - 1728; in = Wo; out = Wot;  K = 768;  N = 768;  nbx = 24; }
    else if (id < 4608) { rel = id - 2304; in = W1; out = W1t;  K = 768;  N = 3072; nbx = 96; }
    else                { rel = id - 4608; in = W2; out = W2t;  K = 3072; N = 768;  nbx = 24; }
    int n0 = (rel % nbx) * 32, k0 = (rel / nbx) * 32;
    __shared__ float tile[32][33];
    #pragma unroll
    for (int r = 0; r < 4; r++)
        tile[ty + r * 8][tx] = in[(size_t)(k0 + ty + r * 8) * N + n0 + tx];
    __syncthreads();
    #pragma unroll
    for (int r = 0; r < 4; r++)
        out[(size_t)(n0 + ty + r * 8) * K + k0 + tx] = f2bf(tile[tx][ty + r * 8]);
}

// ---------------------------------------------------------------------------
// bf16 MFMA GEMM, 128x128 tile, operand-swapped vectorized epilogue.
// ---------------------------------------------------------------------------
template<int OUT_BF16, int RELU>
__global__ __launch_bounds__(256) void gemm_mfma_kernel(
    const unsigned short* __restrict__ A, const unsigned short* __restrict__ Bt,
    const float* __restrict__ bias, const float* __restrict__ resid,
    void* __restrict__ Cout, int M, int N, int K)
{
    __shared__ unsigned short Asm[128 * 32];
    __shared__ unsigned short Bsm[128 * 32];

    int t = threadIdx.x;
    int lane = t & 63, wv = t >> 6;
    int wm = wv & 1, wn = wv >> 1;
    int l16 = lane & 15, quad = lane >> 4;

    int bm = blockIdx.x * 128;
    int bn = blockIdx.y * 128;

    const unsigned short* Abase = A  + (size_t)bm * K;
    const unsigned short* Bbase = Bt + (size_t)bn * K;

    int fl0 = t, fl1 = 256 + t;
    int r0s = fl0 >> 2, kc0 = (fl0 & 3) << 3;
    int r1s = fl1 >> 2, kc1 = (fl1 & 3) << 3;

    f4 acc[4][4] = {};   // acc[j][i]: j = weight (col) tile, i = act (row) tile

    for (int k0 = 0; k0 < K; k0 += 32) {
        __syncthreads();
        GLOBAL_LOAD_LDS16(Abase + (size_t)r0s * K + k0 + kc0, &Asm[fl0 * 8]);
        GLOBAL_LOAD_LDS16(Abase + (size_t)r1s * K + k0 + kc1, &Asm[fl1 * 8]);
        GLOBAL_LOAD_LDS16(Bbase + (size_t)r0s * K + k0 + kc0, &Bsm[fl0 * 8]);
        GLOBAL_LOAD_LDS16(Bbase + (size_t)r1s * K + k0 + kc1, &Bsm[fl1 * 8]);
        __syncthreads();

        bf16x8 xf[4], wf[4];
        #pragma unroll
        for (int i = 0; i < 4; i++) {
            int m = wm * 64 + i * 16 + l16;
            xf[i] = __builtin_bit_cast(bf16x8, *(const i4*)&Asm[m * 32 + quad * 8]);
        }
        #pragma unroll
        for (int j = 0; j < 4; j++) {
            int n = wn * 64 + j * 16 + l16;
            wf[j] = __builtin_bit_cast(bf16x8, *(const i4*)&Bsm[n * 32 + quad * 8]);
        }
        #pragma unroll
        for (int j = 0; j < 4; j++)
            #pragma unroll
            for (int i = 0; i < 4; i++)
                acc[j][i] = __builtin_amdgcn_mfma_f32_16x16x32_bf16(wf[j], xf[i], acc[j][i], 0, 0, 0);
    }

    #pragma unroll
    for (int i = 0; i < 4; i++) {
        int rowg = bm + wm * 64 + i * 16 + l16;
        #pragma unroll
        for (int j = 0; j < 4; j++) {
            int colg0 = bn + wn * 64 + j * 16 + quad * 4;
            f4 v = acc[j][i];
            f4 b4 = *(const f4*)&bias[colg0];
            v += b4;
            if (RELU) {
                #pragma unroll
                for (int r = 0; r < 4; r++) v[r] = fmaxf(v[r], 0.f);
            }
            if (resid) {
                f4 r4 = *(const f4*)&resid[(size_t)rowg * N + colg0];
                v += r4;
            }
            if (OUT_BF16) {
                us4 o;
                o.x = f2bf(v[0]); o.y = f2bf(v[1]); o.z = f2bf(v[2]); o.w = f2bf(v[3]);
                *(us4*)((unsigned short*)Cout + (size_t)rowg * N + colg0) = o;
            } else {
                *(f4*)((float*)Cout + (size_t)rowg * N + colg0) = v;
            }
        }
    }
}

// ---------------------------------------------------------------------------
// bf16 MFMA GEMM, 128x64 tile (for N=768 GEMMs: 3 blocks/CU instead of 1.5).
// ---------------------------------------------------------------------------
template<int OUT_BF16, int RELU>
__global__ __launch_bounds__(256) void gemm_mfma_n64_kernel(
    const unsigned short* __restrict__ A, const unsigned short* __restrict__ Bt,
    const float* __restrict__ bias, const float* __restrict__ resid,
    void* __restrict__ Cout, int M, int N, int K)
{
    __shared__ unsigned short Asm[128 * 32];
    __shared__ unsigned short Bsm[64 * 32];

    int t = threadIdx.x;
    int lane = t & 63, wv = t >> 6;
    int wm = wv & 1, wn = wv >> 1;
    int l16 = lane & 15, quad = lane >> 4;

    int bm = blockIdx.x * 128;
    int bn = blockIdx.y * 64;

    const unsigned short* Abase = A  + (size_t)bm * K;
    const unsigned short* Bbase = Bt + (size_t)bn * K;

    int fl0 = t, fl1 = 256 + t;
    int r0s = fl0 >> 2, kc0 = (fl0 & 3) << 3;
    int r1s = fl1 >> 2, kc1 = (fl1 & 3) << 3;

    f4 acc[2][4] = {};

    for (int k0 = 0; k0 < K; k0 += 32) {
        __syncthreads();
        GLOBAL_LOAD_LDS16(Abase + (size_t)r0s * K + k0 + kc0, &Asm[fl0 * 8]);
        GLOBAL_LOAD_LDS16(Abase + (size_t)r1s * K + k0 + kc1, &Asm[fl1 * 8]);
        GLOBAL_LOAD_LDS16(Bbase + (size_t)r0s * K + k0 + kc0, &Bsm[fl0 * 8]);
        __syncthreads();

        bf16x8 xf[4], wf[2];
        #pragma unroll
        for (int i = 0; i < 4; i++) {
            int m = wm * 64 + i * 16 + l16;
            xf[i] = __builtin_bit_cast(bf16x8, *(const i4*)&Asm[m * 32 + quad * 8]);
        }
        #pragma unroll
        for (int j = 0; j < 2; j++) {
            int n = wn * 32 + j * 16 + l16;
            wf[j] = __builtin_bit_cast(bf16x8, *(const i4*)&Bsm[n * 32 + quad * 8]);
        }
        #pragma unroll
        for (int j = 0; j < 2; j++)
            #pragma unroll
            for (int i = 0; i < 4; i++)
                acc[j][i] = __builtin_amdgcn_mfma_f32_16x16x32_bf16(wf[j], xf[i], acc[j][i], 0, 0, 0);
    }

    #pragma unroll
    for (int i = 0; i < 4; i++) {
        int rowg = bm + wm * 64 + i * 16 + l16;
        #pragma unroll
        for (int j = 0; j < 2; j++) {
            int colg0 = bn + wn * 32 + j * 16 + quad * 4;
            f4 v = acc[j][i];
            f4 b4 = *(const f4*)&bias[colg0];
            v += b4;
            if (RELU) {
                #pragma unroll
                for (int r = 0; r < 4; r++) v[r] = fmaxf(v[r], 0.f);
            }
            if (resid) {
                f4 r4 = *(const f4*)&resid[(size_t)rowg * N + colg0];
                v += r4;
            }
            if (OUT_BF16) {
                us4 o;
                o.x = f2bf(v[0]); o.y = f2bf(v[1]); o.z = f2bf(v[2]); o.w = f2bf(v[3]);
                *(us4*)((unsigned short*)Cout + (size_t)rowg * N + colg0) = o;
            } else {
                *(f4*)((float*)Cout + (size_t)rowg * N + colg0) = v;
            }
        }
    }
}

// ---------------------------------------------------------------------------
// q2/k2 norms from fused qkv bf16 buffer [NTOK][2304] -> q2g,k2g [B*H*S] fp32
// ---------------------------------------------------------------------------
__global__ __launch_bounds__(256) void norms_kernel(
    const unsigned short* __restrict__ qkv, float* __restrict__ q2g, float* __restrict__ k2g)
{
    int row = blockIdx.x;
    int t = threadIdx.x;
    int hh = t >> 5, l32 = t & 31;
    const unsigned short* base = qkv + (size_t)row * QKVW + hh * DH_ + l32 * 3;
    float qs = 0.f, ks = 0.f;
    #pragma unroll
    for (int e = 0; e < 3; e++) {
        float qv = bf2f(base[e]);
        float kv = bf2f(base[768 + e]);
        qs += qv * qv; ks += kv * kv;
    }
    #pragma unroll
    for (int off = 16; off > 0; off >>= 1) {
        qs += __shfl_xor(qs, off, 32);
        ks += __shfl_xor(ks, off, 32);
    }
    if (l32 == 0) {
        int b = row >> 10, s = row & 1023;
        int idx = (b * H_ + hh) * S_ + s;
        q2g[idx] = qs; k2g[idx] = ks;
    }
}

// ---------------------------------------------------------------------------
// V transpose into padded tiles: qkv V-part -> vt[(bh*16+kt)] tile of [96][72] bf16
// ---------------------------------------------------------------------------
__global__ __launch_bounds__(256) void vtrans_kernel(
    const unsigned short* __restrict__ qkv, unsigned short* __restrict__ vt)
{
    __shared__ unsigned short Vl[64][100];
    int blk = blockIdx.x;          // bh*16 + kt
    int bh = blk >> 4, kt = blk & 15;
    int b = bh >> 3, hh = bh & 7;
    int t = threadIdx.x;
    int key = t >> 2, qc = t & 3;
    const unsigned short* src = qkv + ((size_t)(b * S_ + kt * 64 + key)) * QKVW + 1536 + hh * DH_;
    #pragma unroll
    for (int i = 0; i < 3; i++) {
        int chunk = qc + i * 4;            // 0..11, 8 shorts each
        us8 v = *(const us8*)(src + chunk * 8);
        #pragma unroll
        for (int e = 0; e < 8; e++) Vl[key][chunk * 8 + e] = v[e];
    }
    __syncthreads();
    unsigned short* dst = vt + (size_t)blk * 7168;
    #pragma unroll
    for (int r = 0; r < 3; r++) {
        int c = r * 256 + t;               // 0..767
        int vd = c >> 3, kc = c & 7;
        us8 o;
        #pragma unroll
        for (int j = 0; j < 8; j++) o[j] = Vl[kc * 8 + j][vd];
        *(us8*)(dst + vd * 72 + kc * 8) = o;
    }
}

// ---------------------------------------------------------------------------
// MFMA flash attention with L2 distances. NO online max: scores = -dist/sqrt(DH)
// are always <= 0, so max=0 is a valid stable softmax shift (underflow would
// need dist > 800; actual dist is O(10)). l-reduction deferred to epilogue.
// grid = 64 heads * 16 qtiles = 1024 blocks; 4 waves; wave = 16 q-rows; TK=64.
// ---------------------------------------------------------------------------
__global__ __launch_bounds__(256, 4) void attn_mfma_kernel(
    const unsigned short* __restrict__ qkv,
    const unsigned short* __restrict__ vt,
    const float* __restrict__ q2g, const float* __restrict__ k2g,
    unsigned short* __restrict__ outb)
{
    __shared__ unsigned short Klds[64 * 96];     // [key][d]
    __shared__ unsigned short Vlds[7168];        // [vdim][72]
    __shared__ unsigned short Plds[4][16 * 72];  // per-wave [qrow][key], stride 72

    int t = threadIdx.x;
    int lane = t & 63, w = t >> 6;
    int l16 = lane & 15, quad = lane >> 4;

    int bh = blockIdx.x >> 4;
    int qt = blockIdx.x & 15;
    int b = bh >> 3, hh = bh & 7;

    int qrow0 = qt * 64 + w * 16;

    const unsigned short* qb = qkv + ((size_t)(b * S_ + qrow0)) * QKVW + hh * DH_;
    bf16x8 qf[3];
    #pragma unroll
    for (int d = 0; d < 3; d++)
        qf[d] = __builtin_bit_cast(bf16x8,
            *(const i4*)(qb + (size_t)l16 * QKVW + d * 32 + quad * 8));

    float q2n = q2g[bh * S_ + qrow0 + l16];

    float lsum = 0.f;          // per-lane partial (this lane's keys only)
    f4 Oacc[6] = {};

    const float cexp = 0.14724445f;   // log2(e)/sqrt(96)

    const unsigned short* kgb = qkv + ((size_t)(b * S_)) * QKVW + 768 + hh * DH_;
    const unsigned short* vgb0 = vt + (size_t)(bh * 16) * 7168;

    for (int it = 0; it < 16; it++) {
        __syncthreads();
        #pragma unroll
        for (int r = 0; r < 3; r++) {
            int c = r * 256 + t;
            int key = c / 12, dc = c % 12;
            GLOBAL_LOAD_LDS16(kgb + ((size_t)(it * 64 + key)) * QKVW + dc * 8, &Klds[c * 8]);
        }
        const unsigned short* vgb = vgb0 + (size_t)it * 7168;
        #pragma unroll
        for (int r = 0; r < 3; r++)
            GLOBAL_LOAD_LDS16(vgb + (r * 256 + t) * 8, &Vlds[(r * 256 + t) * 8]);
        if (t < 128)
            GLOBAL_LOAD_LDS16(vgb + (768 + t) * 8, &Vlds[(768 + t) * 8]);
        __syncthreads();

        // S^T = K . Q^T : C-frag col(l16)=qrow, row(quad*4+r)=key
        #pragma unroll
        for (int kt2 = 0; kt2 < 4; kt2++) {
            bf16x8 kf0 = __builtin_bit_cast(bf16x8, *(const i4*)&Klds[(kt2 * 16 + l16) * 96 + quad * 8]);
            bf16x8 kf1 = __builtin_bit_cast(bf16x8, *(const i4*)&Klds[(kt2 * 16 + l16) * 96 + 32 + quad * 8]);
            bf16x8 kf2 = __builtin_bit_cast(bf16x8, *(const i4*)&Klds[(kt2 * 16 + l16) * 96 + 64 + quad * 8]);
            f4 a = {};
            a = __builtin_amdgcn_mfma_f32_16x16x32_bf16(kf0, qf[0], a, 0, 0, 0);
            a = __builtin_amdgcn_mfma_f32_16x16x32_bf16(kf1, qf[1], a, 0, 0, 0);
            a = __builtin_amdgcn_mfma_f32_16x16x32_bf16(kf2, qf[2], a, 0, 0, 0);
            // p = exp2(-sqrt(max(q2+k2-2qk,0)) * log2e/sqrt(DH)); accumulate l; pack
            float4 k2f = *(const float4*)(k2g + bh * S_ + it * 64 + kt2 * 16 + quad * 4);
            float pk2[4] = {k2f.x + q2n, k2f.y + q2n, k2f.z + q2n, k2f.w + q2n};
            #pragma unroll
            for (int r2 = 0; r2 < 4; r2++) {
                float d2 = fmaxf(pk2[r2] - 2.f * a[r2], 0.f);
                float p = exp2f(-__builtin_amdgcn_sqrtf(d2) * cexp);
                lsum += p;
                a[r2] = p;
            }
            uint2 pkd;
            pkd.x = (unsigned)f2bf(a[0]) | ((unsigned)f2bf(a[1]) << 16);
            pkd.y = (unsigned)f2bf(a[2]) | ((unsigned)f2bf(a[3]) << 16);
            *(uint2*)&Plds[w][l16 * 72 + kt2 * 16 + quad * 4] = pkd;
        }
        // O += P . V (no rescale needed: fixed shift)
        bf16x8 pa0 = __builtin_bit_cast(bf16x8, *(const i4*)&Plds[w][l16 * 72 + quad * 8]);
        bf16x8 pa1 = __builtin_bit_cast(bf16x8, *(const i4*)&Plds[w][l16 * 72 + 32 + quad * 8]);
        #pragma unroll
        for (int vtl = 0; vtl < 6; vtl++) {
            bf16x8 vf0 = __builtin_bit_cast(bf16x8, *(const i4*)&Vlds[(vtl * 16 + l16) * 72 + quad * 8]);
            bf16x8 vf1 = __builtin_bit_cast(bf16x8, *(const i4*)&Vlds[(vtl * 16 + l16) * 72 + 32 + quad * 8]);
            Oacc[vtl] = __builtin_amdgcn_mfma_f32_16x16x32_bf16(pa0, vf0, Oacc[vtl], 0, 0, 0);
            Oacc[vtl] = __builtin_amdgcn_mfma_f32_16x16x32_bf16(pa1, vf1, Oacc[vtl], 0, 0, 0);
        }
    }
    // single deferred l-reduction over the 4 quads
    lsum += __shfl_xor(lsum, 16, 64);
    lsum += __shfl_xor(lsum, 32, 64);
    float inv_l = 1.f / lsum;
    f4 iv;
    #pragma unroll
    for (int r2 = 0; r2 < 4; r2++)
        iv[r2] = __shfl(inv_l, quad * 4 + r2, 64);
    #pragma unroll
    for (int vtl = 0; vtl < 6; vtl++)
        #pragma unroll
        for (int r2 = 0; r2 < 4; r2++) {
            int row = b * S_ + qrow0 + quad * 4 + r2;
            outb[(size_t)row * D_ + hh * DH_ + vtl * 16 + l16] = f2bf(Oacc[vtl][r2] * iv[r2]);
        }
}

// ---------------------------------------------------------------------------
extern "C" void kernel_launch(void* const* d_in, const int* in_sizes, int n_in,
                              void* d_out, int out_size, void* d_ws, size_t ws_size,
                              hipStream_t stream)
{
    const float* h    = (const float*)d_in[0];
    const float* x    = (const float*)d_in[1];
    const float* g1   = (const float*)d_in[2];
    const float* be1  = (const float*)d_in[3];
    const float* ln1w = (const float*)d_in[4];
    const float* ln1b = (const float*)d_in[5];
    const float* g2   = (const float*)d_in[6];
    const float* be2  = (const float*)d_in[7];
    const float* ln2w = (const float*)d_in[8];
    const float* ln2b = (const float*)d_in[9];
    const float* Wq   = (const float*)d_in[10];
    const float* bq   = (const float*)d_in[11];
    const float* Wk   = (const float*)d_in[12];
    const float* bk   = (const float*)d_in[13];
    const float* Wv   = (const float*)d_in[14];
    const float* bv   = (const float*)d_in[15];
    const float* Wo   = (const float*)d_in[16];
    const float* bo   = (const float*)d_in[17];
    const float* W1   = (const float*)d_in[18];
    const float* b1   = (const float*)d_in[19];
    const float* W2   = (const float*)d_in[20];
    const float* b2   = (const float*)d_in[21];

    float* out = (float*)d_out;
    char* wsb = (char*)d_ws;
    const size_t ND = (size_t)NTOK * D_;

    // workspace layout (bytes): persistent region first, dead-pool last so
    // the full-size MLP hidden (50.3 MB bf16) can overlay the dead pool.
    size_t off = 0;
    unsigned short* W1t = (unsigned short*)(wsb + off); off += 4718592;       // [3072][768]
    unsigned short* W2t = (unsigned short*)(wsb + off); off += 4718592;       // [768][3072]
    float* bqkv = (float*)(wsb + off);                  off += 16384;
    float* htmp = (float*)(wsb + off);                  off += ND * 4;        // fp32
    float* q2g  = (float*)(wsb + off);                  off += (size_t)B_ * H_ * S_ * 4;
    float* k2g  = (float*)(wsb + off);                  off += (size_t)B_ * H_ * S_ * 4;
    unsigned short* h2b = (unsigned short*)(wsb + off); off += ND * 2;        // SLN2 out
    // ---- dead pool (all dead before the MLP) ----
    size_t pool0 = off;
    unsigned short* Wqkvt = (unsigned short*)(wsb + off); off += 3538944;     // [2304][768]
    unsigned short* Wot   = (unsigned short*)(wsb + off); off += 1179648;     // [768][768]
    unsigned short* h1b   = (unsigned short*)(wsb + off); off += ND * 2;      // alias: attnb
    unsigned short* vtg   = (unsigned short*)(wsb + off); off += (size_t)1024 * 14336;
    unsigned short* qkvb  = (unsigned short*)(wsb + off); off += (size_t)NTOK * QKVW * 2;
    unsigned short* attnb   = h1b;
    unsigned short* hiddenb = (unsigned short*)(wsb + pool0);  // [8192][3072] bf16 overlay

    // --- weight prep: single merged kernel (6 transposes + bias concat) ---
    prep_all_kernel<<<6921, dim3(32, 8), 0, stream>>>(
        Wq, Wk, Wv, Wo, W1, W2, bq, bk, bv, Wqkvt, Wot, W1t, W2t, bqkv);

    // 1. SLN1 -> h1b (bf16), copy x -> out[0:ND]
    sln_kernel<<<NTOK, 192, 0, stream>>>(h, x, g1, be1, ln1w, ln1b, h1b, out);

    // 2. fused QKV GEMM: [8192,768] @ [768,2304] -> qkvb bf16
    gemm_mfma_kernel<1, 0><<<dim3(NTOK/128, QKVW/128), 256, 0, stream>>>(
        h1b, Wqkvt, bqkv, nullptr, qkvb, NTOK, QKVW, D_);

    // 3. norms + V transpose tiles
    norms_kernel<<<NTOK, 256, 0, stream>>>(qkvb, q2g, k2g);
    vtrans_kernel<<<1024, 256, 0, stream>>>(qkvb, vtg);

    // 4. MFMA attention -> attnb bf16
    attn_mfma_kernel<<<1024, 256, 0, stream>>>(qkvb, vtg, q2g, k2g, attnb);

    // 5. Wo projection + residual h -> htmp fp32 (128x64 tiles: 768 blocks)
    gemm_mfma_n64_kernel<0, 0><<<dim3(NTOK/128, D_/64), 256, 0, stream>>>(
        attnb, Wot, bo, h, htmp, NTOK, D_, D_);

    // 6. SLN2 -> h2b bf16
    sln_kernel<<<NTOK, 192, 0, stream>>>(htmp, x, g2, be2, ln2w, ln2b, h2b, nullptr);

    // 7. MLP, full-size single dispatches
    gemm_mfma_kernel<1, 1><<<dim3(NTOK/128, DFF_/128), 256, 0, stream>>>(
        h2b, W1t, b1, nullptr, hiddenb, NTOK, DFF_, D_);
    gemm_mfma_n64_kernel<0, 0><<<dim3(NTOK/128, D_/64), 256, 0, stream>>>(
        hiddenb, W2t, b2, htmp, out + ND, NTOK, D_, DFF_);

    (void)in_sizes; (void)n_in; (void)out_size; (void)ws_size;
}